// Round 1
// baseline (3887.994 us; speedup 1.0000x reference)
//
#include <hip/hip_runtime.h>
#include <math.h>

// ---- static dims ----
#define Bsz 8
#define Cc 3
#define Tt 2
#define GH 16
#define GW 16
#define HW 256
#define Dd 512
#define HEADS 8
#define DH 64
#define INNER 512
#define FF 2048
#define Qq 256
#define Kk 1024
#define CPP 768
#define SCALE 0.125f

// ======================= helpers =======================
__device__ __forceinline__ float wred_sum(float v) {
#pragma unroll
  for (int o = 32; o; o >>= 1) v += __shfl_xor(v, o, 64);
  return v;
}
__device__ __forceinline__ float wred_max(float v) {
#pragma unroll
  for (int o = 32; o; o >>= 1) v = fmaxf(v, __shfl_xor(v, o, 64));
  return v;
}
__device__ __forceinline__ float gelu_tanh(float x) {
  float x3 = x * x * x;
  return 0.5f * x * (1.0f + tanhf(0.7978845608028654f * (x + 0.044715f * x3)));
}

// ======================= GEMM: C[M,N] = A[M,K] @ W[K,N] (+bias)(+gelu)(+res) =======================
// M,N multiples of 64; K multiple of 16. 256 threads, 64x64 tile, 4x4 microtile.
template <bool GELU, bool BIAS, bool RES>
__global__ __launch_bounds__(256) void gemm_k(const float* __restrict__ A,
                                              const float* __restrict__ W,
                                              const float* __restrict__ bias,
                                              const float* __restrict__ res,
                                              float* __restrict__ C,
                                              int M, int N, int K) {
  __shared__ float As[16][68];
  __shared__ float Bs[16][68];
  const int tid = threadIdx.x;
  const int tx = tid & 15, ty = tid >> 4;
  const int n0 = blockIdx.x * 64, m0 = blockIdx.y * 64;
  float acc[4][4] = {};
  for (int k0 = 0; k0 < K; k0 += 16) {
    const int rr = tid >> 4, kk = tid & 15;
#pragma unroll
    for (int r = 0; r < 4; ++r)
      As[kk][rr + r * 16] = A[(size_t)(m0 + rr + r * 16) * K + k0 + kk];
    const int kb = tid >> 6, nn = tid & 63;
#pragma unroll
    for (int r = 0; r < 4; ++r)
      Bs[kb + r * 4][nn] = W[(size_t)(k0 + kb + r * 4) * N + n0 + nn];
    __syncthreads();
#pragma unroll
    for (int k = 0; k < 16; ++k) {
      const float4 a4 = *(const float4*)&As[k][ty * 4];
      const float4 b4 = *(const float4*)&Bs[k][tx * 4];
      const float a[4] = {a4.x, a4.y, a4.z, a4.w};
      const float b[4] = {b4.x, b4.y, b4.z, b4.w};
#pragma unroll
      for (int i = 0; i < 4; ++i)
#pragma unroll
        for (int j = 0; j < 4; ++j) acc[i][j] += a[i] * b[j];
    }
    __syncthreads();
  }
#pragma unroll
  for (int i = 0; i < 4; ++i) {
    const int m = m0 + ty * 4 + i;
#pragma unroll
    for (int j = 0; j < 4; ++j) {
      const int n = n0 + tx * 4 + j;
      float v = acc[i][j];
      if (BIAS) v += bias[n];
      if (GELU) v = gelu_tanh(v);
      if (RES) v += res[(size_t)m * N + n];
      C[(size_t)m * N + n] = v;
    }
  }
}

static void gemm(hipStream_t st, const float* A, const float* W, const float* bias,
                 const float* res, float* C, int M, int N, int K, bool gelu) {
  dim3 g(N / 64, M / 64);
  if (gelu)
    gemm_k<true, true, false><<<g, 256, 0, st>>>(A, W, bias, res, C, M, N, K);
  else if (bias && res)
    gemm_k<false, true, true><<<g, 256, 0, st>>>(A, W, bias, res, C, M, N, K);
  else if (bias)
    gemm_k<false, true, false><<<g, 256, 0, st>>>(A, W, bias, res, C, M, N, K);
  else if (res)
    gemm_k<false, false, true><<<g, 256, 0, st>>>(A, W, bias, res, C, M, N, K);
  else
    gemm_k<false, false, false><<<g, 256, 0, st>>>(A, W, bias, res, C, M, N, K);
}

// ======================= patch gather + LN(768) =======================
__global__ __launch_bounds__(256) void pembed_k(const float* __restrict__ video,
                                                const float* __restrict__ g,
                                                const float* __restrict__ b,
                                                float* __restrict__ xpe) {
  const int row = blockIdx.x;  // (b,t,gh,gw)
  const int gw_ = row & 15, gh_ = (row >> 4) & 15, t = (row >> 8) & 1, bb = row >> 9;
  const int tid = threadIdx.x;
  float v[3];
  float s = 0.f, ss = 0.f;
#pragma unroll
  for (int r = 0; r < 3; ++r) {
    const int e = tid + r * 256;
    const int c = e >> 8, rem = e & 255, p1 = rem >> 4, p2 = rem & 15;
    v[r] = video[((size_t)(((bb * 3 + c) * 2 + t) * 256 + gh_ * 16 + p1)) * 256 + gw_ * 16 + p2];
    s += v[r];
    ss += v[r] * v[r];
  }
  __shared__ float r1[4], r2[4];
  s = wred_sum(s);
  ss = wred_sum(ss);
  if ((tid & 63) == 0) { r1[tid >> 6] = s; r2[tid >> 6] = ss; }
  __syncthreads();
  const float S = r1[0] + r1[1] + r1[2] + r1[3];
  const float SS = r2[0] + r2[1] + r2[2] + r2[3];
  const float mean = S * (1.0f / 768.0f);
  const float var = SS * (1.0f / 768.0f) - mean * mean;
  const float inv = rsqrtf(var + 1e-5f);
  float* out = xpe + (size_t)row * 768;
#pragma unroll
  for (int r = 0; r < 3; ++r) {
    const int e = tid + r * 256;
    out[e] = (v[r] - mean) * inv * g[e] + b[e];
  }
}

// ======================= LN over 512 =======================
__global__ __launch_bounds__(256) void ln512_k(const float* __restrict__ x,
                                               const float* __restrict__ g,
                                               const float* __restrict__ b,
                                               float* __restrict__ y) {
  const int row = blockIdx.x;
  const int tid = threadIdx.x;
  const float2 v = ((const float2*)(x + (size_t)row * 512))[tid];
  float s = v.x + v.y, ss = v.x * v.x + v.y * v.y;
  __shared__ float r1[4], r2[4];
  s = wred_sum(s);
  ss = wred_sum(ss);
  if ((tid & 63) == 0) { r1[tid >> 6] = s; r2[tid >> 6] = ss; }
  __syncthreads();
  const float S = r1[0] + r1[1] + r1[2] + r1[3];
  const float SS = r2[0] + r2[1] + r2[2] + r2[3];
  const float mean = S * (1.0f / 512.0f);
  const float var = SS * (1.0f / 512.0f) - mean * mean;
  const float inv = rsqrtf(var + 1e-5f);
  const float2 gg = ((const float2*)g)[tid];
  const float2 bb = ((const float2*)b)[tid];
  float2 o;
  o.x = (v.x - mean) * inv * gg.x + bb.x;
  o.y = (v.y - mean) * inv * gg.y + bb.y;
  ((float2*)(y + (size_t)row * 512))[tid] = o;
}

// ======================= CPB table (31x31 rel positions x 8 heads) =======================
__global__ __launch_bounds__(64) void cpb_k(const float* __restrict__ w1, const float* __restrict__ b1,
                                            const float* __restrict__ w2, const float* __restrict__ b2,
                                            float* __restrict__ table) {
  const int r = blockIdx.x;  // 0..960
  const float ry = (float)(r / 31 - 15), rx = (float)(r % 31 - 15);
  const int lane = threadIdx.x;
  float o[8] = {};
  for (int k = lane; k < 512; k += 64) {
    const float h = fmaxf(ry * w1[k] + rx * w1[512 + k] + b1[k], 0.0f);
#pragma unroll
    for (int j = 0; j < 8; ++j) o[j] += h * w2[k * 8 + j];
  }
#pragma unroll
  for (int j = 0; j < 8; ++j) o[j] = wred_sum(o[j]);
  if (lane == 0)
#pragma unroll
    for (int j = 0; j < 8; ++j) table[r * 8 + j] = o[j] + b2[j];
}

__global__ __launch_bounds__(256) void cpbexpand_k(const float* __restrict__ table,
                                                   float* __restrict__ biasf) {
  const int t = blockIdx.x * 256 + threadIdx.x;  // 65536 (i,j) pairs
  const int i = t >> 8, j = t & 255;
  const int dy = (i >> 4) - (j >> 4) + 15, dx = (i & 15) - (j & 15) + 15;
  const float* e = table + (dy * 31 + dx) * 8;
#pragma unroll
  for (int h = 0; h < 8; ++h) biasf[(size_t)h * 65536 + t] = e[h];
}

// ======================= QK^T (batched, S=256, DH=64) + scale + bias =======================
__global__ __launch_bounds__(256) void qk_k(const float* __restrict__ qkv,
                                            const float* __restrict__ biasf,
                                            float* __restrict__ scores) {
  const int bh = blockIdx.z;  // n*8+h, n in [0,16)
  const int n = bh >> 3, h = bh & 7;
  const int i0 = blockIdx.y * 64, j0 = blockIdx.x * 64;
  const float* Qp = qkv + (size_t)n * 256 * 1536 + h * 64;
  const float* Kp = Qp + 512;
  __shared__ float Qs[16][68], Ks[16][68];
  const int tid = threadIdx.x;
  const int tx = tid & 15, ty = tid >> 4;
  float acc[4][4] = {};
  for (int k0 = 0; k0 < 64; k0 += 16) {
    const int rr = tid >> 4, kk = tid & 15;
#pragma unroll
    for (int r = 0; r < 4; ++r) {
      Qs[kk][rr + r * 16] = Qp[(size_t)(i0 + rr + r * 16) * 1536 + k0 + kk];
      Ks[kk][rr + r * 16] = Kp[(size_t)(j0 + rr + r * 16) * 1536 + k0 + kk];
    }
    __syncthreads();
#pragma unroll
    for (int k = 0; k < 16; ++k) {
      const float4 a4 = *(const float4*)&Qs[k][ty * 4];
      const float4 b4 = *(const float4*)&Ks[k][tx * 4];
      const float a[4] = {a4.x, a4.y, a4.z, a4.w};
      const float b[4] = {b4.x, b4.y, b4.z, b4.w};
#pragma unroll
      for (int i = 0; i < 4; ++i)
#pragma unroll
        for (int j = 0; j < 4; ++j) acc[i][j] += a[i] * b[j];
    }
    __syncthreads();
  }
  float* Cp = scores + (size_t)bh * 65536;
#pragma unroll
  for (int i = 0; i < 4; ++i) {
    const int ii = i0 + ty * 4 + i;
#pragma unroll
    for (int j = 0; j < 4; ++j) {
      const int jj = j0 + tx * 4 + j;
      Cp[(size_t)ii * 256 + jj] = acc[i][j] * SCALE + biasf[(size_t)h * 65536 + ii * 256 + jj];
    }
  }
}

// ======================= row softmax (256 wide), one wave per row =======================
__global__ __launch_bounds__(256) void softmax_k(float* __restrict__ scores) {
  const int wid = threadIdx.x >> 6, lane = threadIdx.x & 63;
  const size_t row = (size_t)blockIdx.x * 4 + wid;
  float4 v = ((float4*)(scores + row * 256))[lane];
  float m = fmaxf(fmaxf(v.x, v.y), fmaxf(v.z, v.w));
  m = wred_max(m);
  v.x = expf(v.x - m); v.y = expf(v.y - m); v.z = expf(v.z - m); v.w = expf(v.w - m);
  float s = v.x + v.y + v.z + v.w;
  s = wred_sum(s);
  const float r = 1.0f / s;
  v.x *= r; v.y *= r; v.z *= r; v.w *= r;
  ((float4*)(scores + row * 256))[lane] = v;
}

// ======================= P @ V (batched 256x64x256) -> attn_out[n*256+i, h*64+d] =======================
__global__ __launch_bounds__(256) void pv_k(const float* __restrict__ scores,
                                            const float* __restrict__ qkv,
                                            float* __restrict__ out) {
  const int bh = blockIdx.z;
  const int n = bh >> 3, h = bh & 7;
  const int i0 = blockIdx.y * 64;
  const float* P = scores + (size_t)bh * 65536;
  const float* V = qkv + (size_t)n * 256 * 1536 + 1024 + h * 64;
  __shared__ float Ps[16][68], Vs[16][68];
  const int tid = threadIdx.x;
  const int tx = tid & 15, ty = tid >> 4;
  float acc[4][4] = {};
  for (int k0 = 0; k0 < 256; k0 += 16) {
    const int rr = tid >> 4, kk = tid & 15;
#pragma unroll
    for (int r = 0; r < 4; ++r)
      Ps[kk][rr + r * 16] = P[(size_t)(i0 + rr + r * 16) * 256 + k0 + kk];
    const int kb = tid >> 6, dd = tid & 63;
#pragma unroll
    for (int r = 0; r < 4; ++r)
      Vs[kb + r * 4][dd] = V[(size_t)(k0 + kb + r * 4) * 1536 + dd];
    __syncthreads();
#pragma unroll
    for (int k = 0; k < 16; ++k) {
      const float4 a4 = *(const float4*)&Ps[k][ty * 4];
      const float4 b4 = *(const float4*)&Vs[k][tx * 4];
      const float a[4] = {a4.x, a4.y, a4.z, a4.w};
      const float b[4] = {b4.x, b4.y, b4.z, b4.w};
#pragma unroll
      for (int i = 0; i < 4; ++i)
#pragma unroll
        for (int j = 0; j < 4; ++j) acc[i][j] += a[i] * b[j];
    }
    __syncthreads();
  }
#pragma unroll
  for (int i = 0; i < 4; ++i)
#pragma unroll
    for (int j = 0; j < 4; ++j)
      out[(size_t)(n * 256 + i0 + ty * 4 + i) * 512 + h * 64 + tx * 4 + j] = acc[i][j];
}

// ======================= temporal attention (S=2), one wave per (n,h) =======================
__global__ __launch_bounds__(256) void tattn_k(const float* __restrict__ qkv,
                                               float* __restrict__ out) {
  const int wid = threadIdx.x >> 6, lane = threadIdx.x & 63;
  const int idx = blockIdx.x * 4 + wid;  // n*8+h, n in [0,2048)
  const int n = idx >> 3, h = idx & 7;
  const float* base = qkv + (size_t)n * 2 * 1536 + h * 64;
  const float q0 = base[lane], q1 = base[1536 + lane];
  const float k0 = base[512 + lane], k1 = base[1536 + 512 + lane];
  const float v0 = base[1024 + lane], v1 = base[1536 + 1024 + lane];
  const float s00 = wred_sum(q0 * k0) * SCALE;
  const float s01 = wred_sum(q0 * k1) * SCALE;
  const float s10 = wred_sum(q1 * k0) * SCALE;
  const float s11 = wred_sum(q1 * k1) * SCALE;
  const float m0 = fmaxf(s00, s01), m1 = fmaxf(s10, s11);
  const float e00 = expf(s00 - m0), e01 = expf(s01 - m0);
  const float e10 = expf(s10 - m1), e11 = expf(s11 - m1);
  const float o0 = (e00 * v0 + e01 * v1) / (e00 + e01);
  const float o1 = (e10 * v0 + e11 * v1) / (e10 + e11);
  out[(size_t)(n * 2 + 0) * 512 + h * 64 + lane] = o0;
  out[(size_t)(n * 2 + 1) * 512 + h * 64 + lane] = o1;
}

// ======================= transposes between [B,T,HW,D] and [B,HW,T,D] =======================
__global__ __launch_bounds__(128) void xpose_fwd_k(const float* __restrict__ src, float* __restrict__ dst) {
  const int dr = blockIdx.x;  // dst row in [B*HW, T]
  const int t = dr & 1, hw = (dr >> 1) & 255, b = dr >> 9;
  const int sr = (b * 2 + t) * 256 + hw;
  ((float4*)(dst + (size_t)dr * 512))[threadIdx.x] = ((const float4*)(src + (size_t)sr * 512))[threadIdx.x];
}
__global__ __launch_bounds__(128) void xpose_bwd_k(const float* __restrict__ src, float* __restrict__ dst) {
  const int dr = blockIdx.x;  // dst row in [B*T, HW]
  const int hw = dr & 255, t = (dr >> 8) & 1, b = dr >> 9;
  const int sr = (b * 256 + hw) * 2 + t;
  ((float4*)(dst + (size_t)dr * 512))[threadIdx.x] = ((const float4*)(src + (size_t)sr * 512))[threadIdx.x];
}

// ======================= feat = mean over HW of tokens[:,1] =======================
__global__ __launch_bounds__(256) void featmean_k(const float* __restrict__ x, float* __restrict__ feat) {
  const int b = blockIdx.x, tid = threadIdx.x;
#pragma unroll
  for (int dd = 0; dd < 2; ++dd) {
    const int d = tid + dd * 256;
    float s = 0.f;
    for (int hw = 0; hw < 256; ++hw)
      s += x[(size_t)((b * 2 + 1) * 256 + hw) * 512 + d];
    feat[b * 512 + d] = s * (1.0f / 256.0f);
  }
}

// ======================= small vec-mat: out[r,:] = A[r,:K] @ W[:, coloff:coloff+N] (+bias) =======================
__global__ __launch_bounds__(256) void vecmat_k(const float* __restrict__ A, int lda,
                                                const float* __restrict__ W, int ldw, int coloff,
                                                const float* __restrict__ bias,
                                                float* __restrict__ out, int ldo, int K, int N) {
  const int r = blockIdx.x;
  __shared__ float av[512];
  for (int k = threadIdx.x; k < K; k += 256) av[k] = A[(size_t)r * lda + k];
  __syncthreads();
  for (int n = threadIdx.x; n < N; n += 256) {
    float s = bias ? bias[n] : 0.0f;
    for (int k = 0; k < K; ++k) s += av[k] * W[(size_t)k * ldw + coloff + n];
    out[(size_t)r * ldo + n] = s;
  }
}

// ======================= VQ: argmin over codebook + err =======================
__global__ __launch_bounds__(256) void vqargmin_k(const float* __restrict__ z,
                                                  const float* __restrict__ cb,
                                                  float* __restrict__ err_out) {
  const int b = blockIdx.x, tid = threadIdx.x;
  __shared__ float zs[256];
  zs[tid] = z[b * 256 + tid];
  __syncthreads();
  float best = 3.4e38f;
  int bi = 0x7fffffff;
  for (int k = tid; k < 1024; k += 256) {
    float d = 0.f;
    for (int q = 0; q < 256; ++q) {
      const float t = zs[q] - cb[(size_t)k * 256 + q];
      d += t * t;
    }
    if (d < best) { best = d; bi = k; }
  }
  __shared__ float bv[256];
  __shared__ int bix[256];
  bv[tid] = best;
  bix[tid] = bi;
  __syncthreads();
  for (int s = 128; s; s >>= 1) {
    if (tid < s) {
      if (bv[tid + s] < bv[tid] || (bv[tid + s] == bv[tid] && bix[tid + s] < bix[tid])) {
        bv[tid] = bv[tid + s];
        bix[tid] = bix[tid + s];
      }
    }
    __syncthreads();
  }
  const int bk = bix[0];
  __syncthreads();
  const float t = zs[tid] - cb[(size_t)bk * 256 + tid];
  float e = wred_sum(t * t);
  if ((tid & 63) == 0) bv[tid >> 6] = e;
  __syncthreads();
  if (tid == 0) err_out[b] = sqrtf(bv[0] + bv[1] + bv[2] + bv[3]);
}

__global__ __launch_bounds__(256) void zq_k(const float* __restrict__ z,
                                            const float* __restrict__ noise,
                                            const float* __restrict__ err,
                                            float* __restrict__ zq) {
  const int b = blockIdx.x, tid = threadIdx.x;
  const float nv = noise[b * 256 + tid];
  __shared__ float red[4];
  float nn = wred_sum(nv * nv);
  if ((tid & 63) == 0) red[tid >> 6] = nn;
  __syncthreads();
  const float norm = sqrtf(red[0] + red[1] + red[2] + red[3]);
  zq[b * 256 + tid] = z[b * 256 + tid] + err[b] / (norm + 1e-8f) * nv;
}

// ======================= cross-attn broadcast add: x[row,:] += u[b(row),:] =======================
__global__ __launch_bounds__(128) void bcastadd_k(float* __restrict__ x, const float* __restrict__ u) {
  const int row = blockIdx.x;
  const int b = row >> 9;
  float4* xr = (float4*)(x + (size_t)row * 512);
  const float4 uv = ((const float4*)(u + (size_t)b * 512))[threadIdx.x];
  float4 v = xr[threadIdx.x];
  v.x += uv.x; v.y += uv.y; v.z += uv.z; v.w += uv.w;
  xr[threadIdx.x] = v;
}

// ======================= scatter pix -> recon [B,C,T,H,W] =======================
__global__ __launch_bounds__(256) void scatter_k(const float* __restrict__ pix, float* __restrict__ out) {
  const int row = blockIdx.x;  // (b,t,gh,gw)
  const int gw_ = row & 15, gh_ = (row >> 4) & 15, t = (row >> 8) & 1, bb = row >> 9;
#pragma unroll
  for (int r = 0; r < 3; ++r) {
    const int e = threadIdx.x + r * 256;
    const int c = e >> 8, rem = e & 255, p1 = rem >> 4, p2 = rem & 15;
    out[((size_t)(((bb * 3 + c) * 2 + t) * 256 + gh_ * 16 + p1)) * 256 + gw_ * 16 + p2] =
        pix[(size_t)row * 768 + e];
  }
}

// ======================= host =======================
extern "C" void kernel_launch(void* const* d_in, const int* in_sizes, int n_in,
                              void* d_out, int out_size, void* d_ws, size_t ws_size,
                              hipStream_t stream) {
  const float* video   = (const float*)d_in[0];
  const float* pe_ln1g = (const float*)d_in[1];
  const float* pe_ln1b = (const float*)d_in[2];
  const float* pe_w    = (const float*)d_in[3];
  const float* pe_b    = (const float*)d_in[4];
  const float* pe_ln2g = (const float*)d_in[5];
  const float* pe_ln2b = (const float*)d_in[6];
  const float* cpb_w1  = (const float*)d_in[7];
  const float* cpb_b1  = (const float*)d_in[8];
  const float* cpb_w2  = (const float*)d_in[9];
  const float* cpb_b2  = (const float*)d_in[10];
  const float* es_ln1g = (const float*)d_in[11];
  const float* es_ln1b = (const float*)d_in[12];
  const float* es_wqkv = (const float*)d_in[13];
  const float* es_wo   = (const float*)d_in[14];
  const float* es_ln2g = (const float*)d_in[15];
  const float* es_ln2b = (const float*)d_in[16];
  const float* es_w1   = (const float*)d_in[17];
  const float* es_b1   = (const float*)d_in[18];
  const float* es_w2   = (const float*)d_in[19];
  const float* es_b2   = (const float*)d_in[20];
  const float* et_ln1g = (const float*)d_in[21];
  const float* et_ln1b = (const float*)d_in[22];
  const float* et_wqkv = (const float*)d_in[23];
  const float* et_wo   = (const float*)d_in[24];
  const float* et_ln2g = (const float*)d_in[25];
  const float* et_ln2b = (const float*)d_in[26];
  const float* et_w1   = (const float*)d_in[27];
  const float* et_b1   = (const float*)d_in[28];
  const float* et_w2   = (const float*)d_in[29];
  const float* et_b2   = (const float*)d_in[30];
  const float* ds_ln1g = (const float*)d_in[31];
  const float* ds_ln1b = (const float*)d_in[32];
  const float* ds_wqkv = (const float*)d_in[33];
  const float* ds_wo   = (const float*)d_in[34];
  // d_in[35] ds_clng, d_in[36] ds_clnb, d_in[37] ds_wq : mathematically dead (L=1 softmax == 1)
  const float* ds_wkv  = (const float*)d_in[38];
  const float* ds_cwo  = (const float*)d_in[39];
  const float* ds_ln2g = (const float*)d_in[40];
  const float* ds_ln2b = (const float*)d_in[41];
  const float* ds_w1   = (const float*)d_in[42];
  const float* ds_b1   = (const float*)d_in[43];
  const float* ds_w2   = (const float*)d_in[44];
  const float* ds_b2   = (const float*)d_in[45];
  const float* vq_inw  = (const float*)d_in[46];
  const float* vq_inb  = (const float*)d_in[47];
  const float* codebook= (const float*)d_in[48];
  const float* vq_outw = (const float*)d_in[49];
  const float* vq_outb = (const float*)d_in[50];
  const float* noise   = (const float*)d_in[51];
  const float* px_w    = (const float*)d_in[52];
  const float* px_b    = (const float*)d_in[53];
  float* out = (float*)d_out;

  // workspace layout (floats)
  float* ws = (float*)d_ws;
  float* xpe  = ws;                   // 4096*768  (also reused for pix)
  float* x    = xpe + 3145728;        // 4096*512
  float* lnb  = x + 2097152;          // 4096*512
  float* qkvb = lnb + 2097152;        // 4096*1536
  float* scr  = qkvb + 6291456;       // 8388608: scores (128*256*256) OR ff1 (4096*2048)
  float* attn = scr + 8388608;        // 4096*512
  float* tmb  = attn + 2097152;       // 4096*512
  float* biasf= tmb + 2097152;        // 8*256*256
  float* table= biasf + 524288;       // 961*8
  float* feat = table + 7688;         // 8*512
  float* zbuf = feat + 4096;          // 8*256
  float* zqb  = zbuf + 2048;          // 8*256
  float* act  = zqb + 2048;           // 8*512
  float* vctx = act + 4096;           // 8*512
  float* ubuf = vctx + 4096;          // 8*512
  float* errb = ubuf + 4096;          // 8

  const int M = 4096;

  // ---- patch embed ----
  pembed_k<<<4096, 256, 0, stream>>>(video, pe_ln1g, pe_ln1b, xpe);
  gemm(stream, xpe, pe_w, pe_b, nullptr, lnb, M, 512, 768, false);
  ln512_k<<<4096, 256, 0, stream>>>(lnb, pe_ln2g, pe_ln2b, x);

  // ---- CPB bias ----
  cpb_k<<<961, 64, 0, stream>>>(cpb_w1, cpb_b1, cpb_w2, cpb_b2, table);
  cpbexpand_k<<<256, 256, 0, stream>>>(table, biasf);

  // ---- encoder spatial (2 layers) ----
  for (int d = 0; d < 2; ++d) {
    ln512_k<<<4096, 256, 0, stream>>>(x, es_ln1g + d * 512, es_ln1b + d * 512, lnb);
    gemm(stream, lnb, es_wqkv + (size_t)d * 512 * 1536, nullptr, nullptr, qkvb, M, 1536, 512, false);
    qk_k<<<dim3(4, 4, 128), 256, 0, stream>>>(qkvb, biasf, scr);
    softmax_k<<<8192, 256, 0, stream>>>(scr);
    pv_k<<<dim3(1, 4, 128), 256, 0, stream>>>(scr, qkvb, attn);
    gemm(stream, attn, es_wo + (size_t)d * 512 * 512, nullptr, x, x, M, 512, 512, false);
    ln512_k<<<4096, 256, 0, stream>>>(x, es_ln2g + d * 512, es_ln2b + d * 512, lnb);
    gemm(stream, lnb, es_w1 + (size_t)d * 512 * 2048, es_b1 + d * 2048, nullptr, scr, M, 2048, 512, true);
    gemm(stream, scr, es_w2 + (size_t)d * 2048 * 512, es_b2 + d * 512, x, x, M, 512, 2048, false);
  }

  // ---- encoder temporal (2 layers) ----
  xpose_fwd_k<<<4096, 128, 0, stream>>>(x, tmb);
  for (int d = 0; d < 2; ++d) {
    ln512_k<<<4096, 256, 0, stream>>>(tmb, et_ln1g + d * 512, et_ln1b + d * 512, lnb);
    gemm(stream, lnb, et_wqkv + (size_t)d * 512 * 1536, nullptr, nullptr, qkvb, M, 1536, 512, false);
    tattn_k<<<4096, 256, 0, stream>>>(qkvb, attn);
    gemm(stream, attn, et_wo + (size_t)d * 512 * 512, nullptr, tmb, tmb, M, 512, 512, false);
    ln512_k<<<4096, 256, 0, stream>>>(tmb, et_ln2g + d * 512, et_ln2b + d * 512, lnb);
    gemm(stream, lnb, et_w1 + (size_t)d * 512 * 2048, et_b1 + d * 2048, nullptr, scr, M, 2048, 512, true);
    gemm(stream, scr, et_w2 + (size_t)d * 2048 * 512, et_b2 + d * 512, tmb, tmb, M, 512, 2048, false);
  }
  xpose_bwd_k<<<4096, 128, 0, stream>>>(tmb, x);

  // ---- NSVQ bottleneck ----
  featmean_k<<<8, 256, 0, stream>>>(x, feat);
  vecmat_k<<<8, 256, 0, stream>>>(feat, 512, vq_inw, 256, 0, vq_inb, zbuf, 256, 512, 256);
  vqargmin_k<<<8, 256, 0, stream>>>(zbuf, codebook, errb);
  zq_k<<<8, 256, 0, stream>>>(zbuf, noise, errb, zqb);
  vecmat_k<<<8, 256, 0, stream>>>(zqb, 256, vq_outw, 512, 0, vq_outb, act, 512, 256, 512);

  // ---- decoder (2 layers) ----
  for (int d = 0; d < 2; ++d) {
    ln512_k<<<4096, 256, 0, stream>>>(x, ds_ln1g + d * 512, ds_ln1b + d * 512, lnb);
    gemm(stream, lnb, ds_wqkv + (size_t)d * 512 * 1536, nullptr, nullptr, qkvb, M, 1536, 512, false);
    qk_k<<<dim3(4, 4, 128), 256, 0, stream>>>(qkvb, biasf, scr);
    softmax_k<<<8192, 256, 0, stream>>>(scr);
    pv_k<<<dim3(1, 4, 128), 256, 0, stream>>>(scr, qkvb, attn);
    gemm(stream, attn, ds_wo + (size_t)d * 512 * 512, nullptr, x, x, M, 512, 512, false);
    // cross-attn: L=1 -> softmax==1 -> out = (ctx @ wkv_v) @ cwo, broadcast over sequence
    vecmat_k<<<8, 256, 0, stream>>>(act, 512, ds_wkv + (size_t)d * 512 * 1024, 1024, 512, nullptr, vctx, 512, 512, 512);
    vecmat_k<<<8, 256, 0, stream>>>(vctx, 512, ds_cwo + (size_t)d * 512 * 512, 512, 0, nullptr, ubuf, 512, 512, 512);
    bcastadd_k<<<4096, 128, 0, stream>>>(x, ubuf);
    ln512_k<<<4096, 256, 0, stream>>>(x, ds_ln2g + d * 512, ds_ln2b + d * 512, lnb);
    gemm(stream, lnb, ds_w1 + (size_t)d * 512 * 2048, ds_b1 + d * 2048, nullptr, scr, M, 2048, 512, true);
    gemm(stream, scr, ds_w2 + (size_t)d * 2048 * 512, ds_b2 + d * 512, x, x, M, 512, 2048, false);
  }

  // ---- pixel head + scatter ----
  gemm(stream, x, px_w, px_b, nullptr, xpe, M, 768, 512, false);
  scatter_k<<<4096, 256, 0, stream>>>(xpe, out);
}

// Round 4
// 2138.169 us; speedup vs baseline: 1.8184x; 1.8184x over previous
//
#include <hip/hip_runtime.h>
#include <math.h>

// ---- static dims ----
#define SCALE 0.125f

typedef unsigned short u16;
typedef short s16x8 __attribute__((ext_vector_type(8)));
typedef u16 u16x8 __attribute__((ext_vector_type(8)));
typedef float f32x4 __attribute__((ext_vector_type(4)));

// ======================= helpers =======================
__device__ __forceinline__ float wred_sum(float v) {
#pragma unroll
  for (int o = 32; o; o >>= 1) v += __shfl_xor(v, o, 64);
  return v;
}
__device__ __forceinline__ float wred_max(float v) {
#pragma unroll
  for (int o = 32; o; o >>= 1) v = fmaxf(v, __shfl_xor(v, o, 64));
  return v;
}
__device__ __forceinline__ float gelu_tanh(float x) {
  float x3 = x * x * x;
  return 0.5f * x * (1.0f + tanhf(0.7978845608028654f * (x + 0.044715f * x3)));
}
__device__ __forceinline__ u16 f2bf(float f) {
  unsigned u = __float_as_uint(f);
  return (u16)((u + 0x7fffu + ((u >> 16) & 1u)) >> 16);
}

// ======================= weight transpose + cast: dst[N][K] bf16 = src[K][N] fp32 ===========
struct TP6 { const float* s0; const float* s1; const float* s2;
             const float* s3; const float* s4; const float* s5; };

__global__ __launch_bounds__(256) void wtrans_k(TP6 p, u16* __restrict__ dst,
                                                int K, int N, size_t mstride) {
  const float* srcs[6] = {p.s0, p.s1, p.s2, p.s3, p.s4, p.s5};
  const float* src = srcs[blockIdx.z];
  u16* d = dst + (size_t)blockIdx.z * mstride;
  __shared__ float t[32][33];
  const int tx = threadIdx.x, ty = threadIdx.y;
  const int n0 = blockIdx.x * 32, k0 = blockIdx.y * 32;
#pragma unroll
  for (int i = 0; i < 4; ++i) t[ty + i * 8][tx] = src[(size_t)(k0 + ty + i * 8) * N + n0 + tx];
  __syncthreads();
#pragma unroll
  for (int i = 0; i < 4; ++i)
    d[(size_t)(n0 + ty + i * 8) * K + k0 + tx] = f2bf(t[tx][ty + i * 8]);
}

// ======================= bf16 MFMA GEMM =======================
// C[M,N] = A[M,K](fp32, cast in-kernel) @ Bt[N,K](bf16)^T  (+bias)(+gelu)(+res)
// 128x128 tile, BK=64, 256 threads (4 waves, 2x2 of 64x64), 16x16x32 MFMA.
template <bool GELU, bool BIAS, bool RES>
__global__ __launch_bounds__(256) void mgemm_k(const float* __restrict__ A,
                                               const u16* __restrict__ Bt,
                                               const float* __restrict__ bias,
                                               const float* __restrict__ res,
                                               float* __restrict__ C,
                                               int M, int N, int K) {
  __shared__ u16 As[128 * 64];
  __shared__ u16 Bs[128 * 64];
  const int tid = threadIdx.x;
  const int lane = tid & 63, wid = tid >> 6;
  const int wr = wid >> 1, wc = wid & 1;
  const int m0 = blockIdx.y * 128, n0 = blockIdx.x * 128;
  f32x4 acc[4][4];
#pragma unroll
  for (int m = 0; m < 4; ++m)
#pragma unroll
    for (int n = 0; n < 4; ++n) acc[m][n] = (f32x4){0.f, 0.f, 0.f, 0.f};

  for (int k0 = 0; k0 < K; k0 += 64) {
    // ---- stage A: 128 rows x 64 k, fp32 -> bf16, XOR-swizzled 16B slots ----
#pragma unroll
    for (int p = 0; p < 4; ++p) {
      const int i = p * 256 + tid;        // 1024 chunks of 8 floats
      const int r = i >> 3, c8 = i & 7;
      const float4* src = (const float4*)&A[(size_t)(m0 + r) * K + k0 + c8 * 8];
      const float4 f0 = src[0], f1 = src[1];
      u16x8 h;
      h[0] = f2bf(f0.x); h[1] = f2bf(f0.y); h[2] = f2bf(f0.z); h[3] = f2bf(f0.w);
      h[4] = f2bf(f1.x); h[5] = f2bf(f1.y); h[6] = f2bf(f1.z); h[7] = f2bf(f1.w);
      const int byte = r * 128 + ((c8 * 16) ^ ((r & 7) << 4));
      *(u16x8*)((char*)As + byte) = h;
    }
    // ---- stage B: 128 n-rows x 64 k bf16 from Bt, swizzled ----
#pragma unroll
    for (int p = 0; p < 4; ++p) {
      const int i = p * 256 + tid;        // 1024 chunks of 16B
      const int r = i >> 3, c = i & 7;
      const u16x8 h = *(const u16x8*)&Bt[(size_t)(n0 + r) * K + k0 + c * 8];
      const int byte = r * 128 + ((c * 16) ^ ((r & 7) << 4));
      *(u16x8*)((char*)Bs + byte) = h;
    }
    __syncthreads();
#pragma unroll
    for (int ks = 0; ks < 2; ++ks) {
      const int kb = ks * 64 + ((lane >> 4) << 4);  // byte offset of this lane's 8 bf16
      s16x8 af[4], bfr[4];
#pragma unroll
      for (int m = 0; m < 4; ++m) {
        const int r = wr * 64 + m * 16 + (lane & 15);
        af[m] = *(const s16x8*)((const char*)As + r * 128 + (kb ^ ((r & 7) << 4)));
      }
#pragma unroll
      for (int n = 0; n < 4; ++n) {
        const int r = wc * 64 + n * 16 + (lane & 15);
        bfr[n] = *(const s16x8*)((const char*)Bs + r * 128 + (kb ^ ((r & 7) << 4)));
      }
#pragma unroll
      for (int m = 0; m < 4; ++m)
#pragma unroll
        for (int n = 0; n < 4; ++n)
          acc[m][n] = __builtin_amdgcn_mfma_f32_16x16x32_bf16(af[m], bfr[n], acc[m][n], 0, 0, 0);
    }
    __syncthreads();
  }
  // ---- epilogue: C/D layout col=lane&15, row=(lane>>4)*4+j ----
#pragma unroll
  for (int m = 0; m < 4; ++m) {
    const int row = m0 + wr * 64 + m * 16 + ((lane >> 4) << 2);
#pragma unroll
    for (int n = 0; n < 4; ++n) {
      const int col = n0 + wc * 64 + n * 16 + (lane & 15);
      const float bs = BIAS ? bias[col] : 0.0f;
#pragma unroll
      for (int j = 0; j < 4; ++j) {
        float v = acc[m][n][j] + bs;
        if (GELU) v = gelu_tanh(v);
        if (RES) v += res[(size_t)(row + j) * N + col];
        C[(size_t)(row + j) * N + col] = v;
      }
    }
  }
}

static void mgemm(hipStream_t st, const float* A, const u16* Bt, const float* bias,
                  const float* res, float* C, int M, int N, int K, bool gelu) {
  dim3 g(N / 128, M / 128);
  if (gelu)
    mgemm_k<true, true, false><<<g, 256, 0, st>>>(A, Bt, bias, res, C, M, N, K);
  else if (bias && res)
    mgemm_k<false, true, true><<<g, 256, 0, st>>>(A, Bt, bias, res, C, M, N, K);
  else if (bias)
    mgemm_k<false, true, false><<<g, 256, 0, st>>>(A, Bt, bias, res, C, M, N, K);
  else if (res)
    mgemm_k<false, false, true><<<g, 256, 0, st>>>(A, Bt, bias, res, C, M, N, K);
  else
    mgemm_k<false, false, false><<<g, 256, 0, st>>>(A, Bt, bias, res, C, M, N, K);
}

// ======================= patch gather + LN(768) =======================
__global__ __launch_bounds__(256) void pembed_k(const float* __restrict__ video,
                                                const float* __restrict__ g,
                                                const float* __restrict__ b,
                                                float* __restrict__ xpe) {
  const int row = blockIdx.x;  // (b,t,gh,gw)
  const int gw_ = row & 15, gh_ = (row >> 4) & 15, t = (row >> 8) & 1, bb = row >> 9;
  const int tid = threadIdx.x;
  float v[3];
  float s = 0.f, ss = 0.f;
#pragma unroll
  for (int r = 0; r < 3; ++r) {
    const int e = tid + r * 256;
    const int c = e >> 8, rem = e & 255, p1 = rem >> 4, p2 = rem & 15;
    v[r] = video[((size_t)(((bb * 3 + c) * 2 + t) * 256 + gh_ * 16 + p1)) * 256 + gw_ * 16 + p2];
    s += v[r];
    ss += v[r] * v[r];
  }
  __shared__ float r1[4], r2[4];
  s = wred_sum(s);
  ss = wred_sum(ss);
  if ((tid & 63) == 0) { r1[tid >> 6] = s; r2[tid >> 6] = ss; }
  __syncthreads();
  const float S = r1[0] + r1[1] + r1[2] + r1[3];
  const float SS = r2[0] + r2[1] + r2[2] + r2[3];
  const float mean = S * (1.0f / 768.0f);
  const float var = SS * (1.0f / 768.0f) - mean * mean;
  const float inv = rsqrtf(var + 1e-5f);
  float* out = xpe + (size_t)row * 768;
#pragma unroll
  for (int r = 0; r < 3; ++r) {
    const int e = tid + r * 256;
    out[e] = (v[r] - mean) * inv * g[e] + b[e];
  }
}

// ======================= LN over 512 =======================
__global__ __launch_bounds__(256) void ln512_k(const float* __restrict__ x,
                                               const float* __restrict__ g,
                                               const float* __restrict__ b,
                                               float* __restrict__ y) {
  const int row = blockIdx.x;
  const int tid = threadIdx.x;
  const float2 v = ((const float2*)(x + (size_t)row * 512))[tid];
  float s = v.x + v.y, ss = v.x * v.x + v.y * v.y;
  __shared__ float r1[4], r2[4];
  s = wred_sum(s);
  ss = wred_sum(ss);
  if ((tid & 63) == 0) { r1[tid >> 6] = s; r2[tid >> 6] = ss; }
  __syncthreads();
  const float S = r1[0] + r1[1] + r1[2] + r1[3];
  const float SS = r2[0] + r2[1] + r2[2] + r2[3];
  const float mean = S * (1.0f / 512.0f);
  const float var = SS * (1.0f / 512.0f) - mean * mean;
  const float inv = rsqrtf(var + 1e-5f);
  const float2 gg = ((const float2*)g)[tid];
  const float2 bb = ((const float2*)b)[tid];
  float2 o;
  o.x = (v.x - mean) * inv * gg.x + bb.x;
  o.y = (v.y - mean) * inv * gg.y + bb.y;
  ((float2*)(y + (size_t)row * 512))[tid] = o;
}

// ======================= CPB table (31x31 rel positions x 8 heads) =======================
__global__ __launch_bounds__(64) void cpb_k(const float* __restrict__ w1, const float* __restrict__ b1,
                                            const float* __restrict__ w2, const float* __restrict__ b2,
                                            float* __restrict__ table) {
  const int r = blockIdx.x;  // 0..960
  const float ry = (float)(r / 31 - 15), rx = (float)(r % 31 - 15);
  const int lane = threadIdx.x;
  float o[8] = {};
  for (int k = lane; k < 512; k += 64) {
    const float h = fmaxf(ry * w1[k] + rx * w1[512 + k] + b1[k], 0.0f);
#pragma unroll
    for (int j = 0; j < 8; ++j) o[j] += h * w2[k * 8 + j];
  }
#pragma unroll
  for (int j = 0; j < 8; ++j) o[j] = wred_sum(o[j]);
  if (lane == 0)
#pragma unroll
    for (int j = 0; j < 8; ++j) table[r * 8 + j] = o[j] + b2[j];
}

__global__ __launch_bounds__(256) void cpbexpand_k(const float* __restrict__ table,
                                                   float* __restrict__ biasf) {
  const int t = blockIdx.x * 256 + threadIdx.x;  // 65536 (i,j) pairs
  const int i = t >> 8, j = t & 255;
  const int dy = (i >> 4) - (j >> 4) + 15, dx = (i & 15) - (j & 15) + 15;
  const float* e = table + (dy * 31 + dx) * 8;
#pragma unroll
  for (int h = 0; h < 8; ++h) biasf[(size_t)h * 65536 + t] = e[h];
}

// ======================= QK^T (batched, S=256, DH=64) + scale + bias =======================
__global__ __launch_bounds__(256) void qk_k(const float* __restrict__ qkv,
                                            const float* __restrict__ biasf,
                                            float* __restrict__ scores) {
  const int bh = blockIdx.z;  // n*8+h, n in [0,16)
  const int n = bh >> 3, h = bh & 7;
  const int i0 = blockIdx.y * 64, j0 = blockIdx.x * 64;
  const float* Qp = qkv + (size_t)n * 256 * 1536 + h * 64;
  const float* Kp = Qp + 512;
  __shared__ float Qs[16][68], Ks[16][68];
  const int tid = threadIdx.x;
  const int tx = tid & 15, ty = tid >> 4;
  float acc[4][4] = {};
  for (int k0 = 0; k0 < 64; k0 += 16) {
    const int rr = tid >> 4, kk = tid & 15;
#pragma unroll
    for (int r = 0; r < 4; ++r) {
      Qs[kk][rr + r * 16] = Qp[(size_t)(i0 + rr + r * 16) * 1536 + k0 + kk];
      Ks[kk][rr + r * 16] = Kp[(size_t)(j0 + rr + r * 16) * 1536 + k0 + kk];
    }
    __syncthreads();
#pragma unroll
    for (int k = 0; k < 16; ++k) {
      const float4 a4 = *(const float4*)&Qs[k][ty * 4];
      const float4 b4 = *(const float4*)&Ks[k][tx * 4];
      const float a[4] = {a4.x, a4.y, a4.z, a4.w};
      const float b[4] = {b4.x, b4.y, b4.z, b4.w};
#pragma unroll
      for (int i = 0; i < 4; ++i)
#pragma unroll
        for (int j = 0; j < 4; ++j) acc[i][j] += a[i] * b[j];
    }
    __syncthreads();
  }
  float* Cp = scores + (size_t)bh * 65536;
#pragma unroll
  for (int i = 0; i < 4; ++i) {
    const int ii = i0 + ty * 4 + i;
#pragma unroll
    for (int j = 0; j < 4; ++j) {
      const int jj = j0 + tx * 4 + j;
      Cp[(size_t)ii * 256 + jj] = acc[i][j] * SCALE + biasf[(size_t)h * 65536 + ii * 256 + jj];
    }
  }
}

// ======================= row softmax (256 wide), one wave per row =======================
__global__ __launch_bounds__(256) void softmax_k(float* __restrict__ scores) {
  const int wid = threadIdx.x >> 6, lane = threadIdx.x & 63;
  const size_t row = (size_t)blockIdx.x * 4 + wid;
  float4 v = ((float4*)(scores + row * 256))[lane];
  float m = fmaxf(fmaxf(v.x, v.y), fmaxf(v.z, v.w));
  m = wred_max(m);
  v.x = expf(v.x - m); v.y = expf(v.y - m); v.z = expf(v.z - m); v.w = expf(v.w - m);
  float s = v.x + v.y + v.z + v.w;
  s = wred_sum(s);
  const float r = 1.0f / s;
  v.x *= r; v.y *= r; v.z *= r; v.w *= r;
  ((float4*)(scores + row * 256))[lane] = v;
}

// ======================= P @ V (batched 256x64x256) =======================
__global__ __launch_bounds__(256) void pv_k(const float* __restrict__ scores,
                                            const float* __restrict__ qkv,
                                            float* __restrict__ out) {
  const int bh = blockIdx.z;
  const int n = bh >> 3, h = bh & 7;
  const int i0 = blockIdx.y * 64;
  const float* P = scores + (size_t)bh * 65536;
  const float* V = qkv + (size_t)n * 256 * 1536 + 1024 + h * 64;
  __shared__ float Ps[16][68], Vs[16][68];
  const int tid = threadIdx.x;
  const int tx = tid & 15, ty = tid >> 4;
  float acc[4][4] = {};
  for (int k0 = 0; k0 < 256; k0 += 16) {
    const int rr = tid >> 4, kk = tid & 15;
#pragma unroll
    for (int r = 0; r < 4; ++r)
      Ps[kk][rr + r * 16] = P[(size_t)(i0 + rr + r * 16) * 256 + k0 + kk];
    const int kb = tid >> 6, dd = tid & 63;
#pragma unroll
    for (int r = 0; r < 4; ++r)
      Vs[kb + r * 4][dd] = V[(size_t)(k0 + kb + r * 4) * 1536 + dd];
    __syncthreads();
#pragma unroll
    for (int k = 0; k < 16; ++k) {
      const float4 a4 = *(const float4*)&Ps[k][ty * 4];
      const float4 b4 = *(const float4*)&Vs[k][tx * 4];
      const float a[4] = {a4.x, a4.y, a4.z, a4.w};
      const float b[4] = {b4.x, b4.y, b4.z, b4.w};
#pragma unroll
      for (int i = 0; i < 4; ++i)
#pragma unroll
        for (int j = 0; j < 4; ++j) acc[i][j] += a[i] * b[j];
    }
    __syncthreads();
  }
#pragma unroll
  for (int i = 0; i < 4; ++i)
#pragma unroll
    for (int j = 0; j < 4; ++j)
      out[(size_t)(n * 256 + i0 + ty * 4 + i) * 512 + h * 64 + tx * 4 + j] = acc[i][j];
}

// ======================= temporal attention (S=2), one wave per (n,h) =======================
__global__ __launch_bounds__(256) void tattn_k(const float* __restrict__ qkv,
                                               float* __restrict__ out) {
  const int wid = threadIdx.x >> 6, lane = threadIdx.x & 63;
  const int idx = blockIdx.x * 4 + wid;  // n*8+h, n in [0,2048)
  const int n = idx >> 3, h = idx & 7;
  const float* base = qkv + (size_t)n * 2 * 1536 + h * 64;
  const float q0 = base[lane], q1 = base[1536 + lane];
  const float k0 = base[512 + lane], k1 = base[1536 + 512 + lane];
  const float v0 = base[1024 + lane], v1 = base[1536 + 1024 + lane];
  const float s00 = wred_sum(q0 * k0) * SCALE;
  const float s01 = wred_sum(q0 * k1) * SCALE;
  const float s10 = wred_sum(q1 * k0) * SCALE;
  const float s11 = wred_sum(q1 * k1) * SCALE;
  const float m0 = fmaxf(s00, s01), m1 = fmaxf(s10, s11);
  const float e00 = expf(s00 - m0), e01 = expf(s01 - m0);
  const float e10 = expf(s10 - m1), e11 = expf(s11 - m1);
  const float o0 = (e00 * v0 + e01 * v1) / (e00 + e01);
  const float o1 = (e10 * v0 + e11 * v1) / (e10 + e11);
  out[(size_t)(n * 2 + 0) * 512 + h * 64 + lane] = o0;
  out[(size_t)(n * 2 + 1) * 512 + h * 64 + lane] = o1;
}

// ======================= transposes between [B,T,HW,D] and [B,HW,T,D] =======================
__global__ __launch_bounds__(128) void xpose_fwd_k(const float* __restrict__ src, float* __restrict__ dst) {
  const int dr = blockIdx.x;  // dst row in [B*HW, T]
  const int t = dr & 1, hw = (dr >> 1) & 255, b = dr >> 9;
  const int sr = (b * 2 + t) * 256 + hw;
  ((float4*)(dst + (size_t)dr * 512))[threadIdx.x] = ((const float4*)(src + (size_t)sr * 512))[threadIdx.x];
}
__global__ __launch_bounds__(128) void xpose_bwd_k(const float* __restrict__ src, float* __restrict__ dst) {
  const int dr = blockIdx.x;  // dst row in [B*T, HW]
  const int hw = dr & 255, t = (dr >> 8) & 1, b = dr >> 9;
  const int sr = (b * 256 + hw) * 2 + t;
  ((float4*)(dst + (size_t)dr * 512))[threadIdx.x] = ((const float4*)(src + (size_t)sr * 512))[threadIdx.x];
}

// ======================= feat = mean over HW of tokens[:,1] =======================
__global__ __launch_bounds__(256) void featmean_k(const float* __restrict__ x, float* __restrict__ feat) {
  const int b = blockIdx.x, tid = threadIdx.x;
#pragma unroll
  for (int dd = 0; dd < 2; ++dd) {
    const int d = tid + dd * 256;
    float s = 0.f;
    for (int hw = 0; hw < 256; ++hw)
      s += x[(size_t)((b * 2 + 1) * 256 + hw) * 512 + d];
    feat[b * 512 + d] = s * (1.0f / 256.0f);
  }
}

// ======================= small vec-mat =======================
__global__ __launch_bounds__(256) void vecmat_k(const float* __restrict__ A, int lda,
                                                const float* __restrict__ W, int ldw, int coloff,
                                                const float* __restrict__ bias,
                                                float* __restrict__ out, int ldo, int K, int N) {
  const int r = blockIdx.x;
  __shared__ float av[512];
  for (int k = threadIdx.x; k < K; k += 256) av[k] = A[(size_t)r * lda + k];
  __syncthreads();
  for (int n = threadIdx.x; n < N; n += 256) {
    float s = bias ? bias[n] : 0.0f;
    for (int k = 0; k < K; ++k) s += av[k] * W[(size_t)k * ldw + coloff + n];
    out[(size_t)r * ldo + n] = s;
  }
}

// ======================= VQ: argmin over codebook + err =======================
__global__ __launch_bounds__(256) void vqargmin_k(const float* __restrict__ z,
                                                  const float* __restrict__ cb,
                                                  float* __restrict__ err_out) {
  const int b = blockIdx.x, tid = threadIdx.x;
  __shared__ float zs[256];
  zs[tid] = z[b * 256 + tid];
  __syncthreads();
  float best = 3.4e38f;
  int bi = 0x7fffffff;
  for (int k = tid; k < 1024; k += 256) {
    float d = 0.f;
    for (int q = 0; q < 256; ++q) {
      const float t = zs[q] - cb[(size_t)k * 256 + q];
      d += t * t;
    }
    if (d < best) { best = d; bi = k; }
  }
  __shared__ float bv[256];
  __shared__ int bix[256];
  bv[tid] = best;
  bix[tid] = bi;
  __syncthreads();
  for (int s = 128; s; s >>= 1) {
    if (tid < s) {
      if (bv[tid + s] < bv[tid] || (bv[tid + s] == bv[tid] && bix[tid + s] < bix[tid])) {
        bv[tid] = bv[tid + s];
        bix[tid] = bix[tid + s];
      }
    }
    __syncthreads();
  }
  const int bk = bix[0];
  __syncthreads();
  const float t = zs[tid] - cb[(size_t)bk * 256 + tid];
  float e = wred_sum(t * t);
  if ((tid & 63) == 0) bv[tid >> 6] = e;
  __syncthreads();
  if (tid == 0) err_out[b] = sqrtf(bv[0] + bv[1] + bv[2] + bv[3]);
}

__global__ __launch_bounds__(256) void zq_k(const float* __restrict__ z,
                                            const float* __restrict__ noise,
                                            const float* __restrict__ err,
                                            float* __restrict__ zq) {
  const int b = blockIdx.x, tid = threadIdx.x;
  const float nv = noise[b * 256 + tid];
  __shared__ float red[4];
  float nn = wred_sum(nv * nv);
  if ((tid & 63) == 0) red[tid >> 6] = nn;
  __syncthreads();
  const float norm = sqrtf(red[0] + red[1] + red[2] + red[3]);
  zq[b * 256 + tid] = z[b * 256 + tid] + err[b] / (norm + 1e-8f) * nv;
}

// ======================= cross-attn broadcast add =======================
__global__ __launch_bounds__(128) void bcastadd_k(float* __restrict__ x, const float* __restrict__ u) {
  const int row = blockIdx.x;
  const int b = row >> 9;
  float4* xr = (float4*)(x + (size_t)row * 512);
  const float4 uv = ((const float4*)(u + (size_t)b * 512))[threadIdx.x];
  float4 v = xr[threadIdx.x];
  v.x += uv.x; v.y += uv.y; v.z += uv.z; v.w += uv.w;
  xr[threadIdx.x] = v;
}

// ======================= scatter pix -> recon [B,C,T,H,W] =======================
__global__ __launch_bounds__(256) void scatter_k(const float* __restrict__ pix, float* __restrict__ out) {
  const int row = blockIdx.x;  // (b,t,gh,gw)
  const int gw_ = row & 15, gh_ = (row >> 4) & 15, t = (row >> 8) & 1, bb = row >> 9;
#pragma unroll
  for (int r = 0; r < 3; ++r) {
    const int e = threadIdx.x + r * 256;
    const int c = e >> 8, rem = e & 255, p1 = rem >> 4, p2 = rem & 15;
    out[((size_t)(((bb * 3 + c) * 2 + t) * 256 + gh_ * 16 + p1)) * 256 + gw_ * 16 + p2] =
        pix[(size_t)row * 768 + e];
  }
}

// ======================= host =======================
extern "C" void kernel_launch(void* const* d_in, const int* in_sizes, int n_in,
                              void* d_out, int out_size, void* d_ws, size_t ws_size,
                              hipStream_t stream) {
  const float* video   = (const float*)d_in[0];
  const float* pe_ln1g = (const float*)d_in[1];
  const float* pe_ln1b = (const float*)d_in[2];
  const float* pe_w    = (const float*)d_in[3];
  const float* pe_b    = (const float*)d_in[4];
  const float* pe_ln2g = (const float*)d_in[5];
  const float* pe_ln2b = (const float*)d_in[6];
  const float* cpb_w1  = (const float*)d_in[7];
  const float* cpb_b1  = (const float*)d_in[8];
  const float* cpb_w2  = (const float*)d_in[9];
  const float* cpb_b2  = (const float*)d_in[10];
  const float* es_ln1g = (const float*)d_in[11];
  const float* es_ln1b = (const float*)d_in[12];
  const float* es_wqkv = (const float*)d_in[13];
  const float* es_wo   = (const float*)d_in[14];
  const float* es_ln2g = (const float*)d_in[15];
  const float* es_ln2b = (const float*)d_in[16];
  const float* es_w1   = (const float*)d_in[17];
  const float* es_b1   = (const float*)d_in[18];
  const float* es_w2   = (const float*)d_in[19];
  const float* es_b2   = (const float*)d_in[20];
  const float* et_ln1g = (const float*)d_in[21];
  const float* et_ln1b = (const float*)d_in[22];
  const float* et_wqkv = (const float*)d_in[23];
  const float* et_wo   = (const float*)d_in[24];
  const float* et_ln2g = (const float*)d_in[25];
  const float* et_ln2b = (const float*)d_in[26];
  const float* et_w1   = (const float*)d_in[27];
  const float* et_b1   = (const float*)d_in[28];
  const float* et_w2   = (const float*)d_in[29];
  const float* et_b2   = (const float*)d_in[30];
  const float* ds_ln1g = (const float*)d_in[31];
  const float* ds_ln1b = (const float*)d_in[32];
  const float* ds_wqkv = (const float*)d_in[33];
  const float* ds_wo   = (const float*)d_in[34];
  // d_in[35..37] ds_clng/ds_clnb/ds_wq: mathematically dead (L=1 softmax == 1)
  const float* ds_wkv  = (const float*)d_in[38];
  const float* ds_cwo  = (const float*)d_in[39];
  const float* ds_ln2g = (const float*)d_in[40];
  const float* ds_ln2b = (const float*)d_in[41];
  const float* ds_w1   = (const float*)d_in[42];
  const float* ds_b1   = (const float*)d_in[43];
  const float* ds_w2   = (const float*)d_in[44];
  const float* ds_b2   = (const float*)d_in[45];
  const float* vq_inw  = (const float*)d_in[46];
  const float* vq_inb  = (const float*)d_in[47];
  const float* codebook= (const float*)d_in[48];
  const float* vq_outw = (const float*)d_in[49];
  const float* vq_outb = (const float*)d_in[50];
  const float* noise   = (const float*)d_in[51];
  const float* px_w    = (const float*)d_in[52];
  const float* px_b    = (const float*)d_in[53];
  float* out = (float*)d_out;

  // workspace layout (floats)
  float* ws = (float*)d_ws;
  float* xpe  = ws;                   // 4096*768  (also reused for pix)
  float* x    = xpe + 3145728;        // 4096*512
  float* lnb  = x + 2097152;          // 4096*512
  float* qkvb = lnb + 2097152;        // 4096*1536
  float* scr  = qkvb + 6291456;       // 8388608: scores OR ff1
  float* attn = scr + 8388608;        // 4096*512
  float* tmb  = attn + 2097152;       // 4096*512
  float* biasf= tmb + 2097152;        // 8*256*256
  float* table= biasf + 524288;       // 961*8
  float* feat = table + 7688;         // 8*512
  float* zbuf = feat + 4096;          // 8*256
  float* zqb  = zbuf + 2048;          // 8*256
  float* act  = zqb + 2048;           // 8*512
  float* vctx = act + 4096;           // 8*512
  float* ubuf = vctx + 4096;          // 8*512
  float* errb = ubuf + 4096;          // 8
  // bf16 transposed weights (ushort), 16B-aligned tail
  u16* wbf    = (u16*)(errb + 8);
  u16* pe_wt  = wbf;                   // 512x768
  u16* qkv_wt = pe_wt + 393216;        // 6 x (1536x512)
  u16* wo_wt  = qkv_wt + 4718592;      // 6 x (512x512)
  u16* w1_wt  = wo_wt + 1572864;       // 6 x (2048x512)
  u16* w2_wt  = w1_wt + 6291456;       // 6 x (512x2048)
  u16* px_wt  = w2_wt + 6291456;       // 768x512

  const int M = 4096;

  // ---- weight cast+transpose (bf16, [N][K]) ----
  {
    TP6 pqkv = {es_wqkv, es_wqkv + 786432, et_wqkv, et_wqkv + 786432, ds_wqkv, ds_wqkv + 786432};
    wtrans_k<<<dim3(48, 16, 6), dim3(32, 8), 0, stream>>>(pqkv, qkv_wt, 512, 1536, 786432);
    TP6 pwo = {es_wo, es_wo + 262144, et_wo, et_wo + 262144, ds_wo, ds_wo + 262144};
    wtrans_k<<<dim3(16, 16, 6), dim3(32, 8), 0, stream>>>(pwo, wo_wt, 512, 512, 262144);
    TP6 pw1 = {es_w1, es_w1 + 1048576, et_w1, et_w1 + 1048576, ds_w1, ds_w1 + 1048576};
    wtrans_k<<<dim3(64, 16, 6), dim3(32, 8), 0, stream>>>(pw1, w1_wt, 512, 2048, 1048576);
    TP6 pw2 = {es_w2, es_w2 + 1048576, et_w2, et_w2 + 1048576, ds_w2, ds_w2 + 1048576};
    wtrans_k<<<dim3(16, 64, 6), dim3(32, 8), 0, stream>>>(pw2, w2_wt, 2048, 512, 1048576);
    TP6 ppe = {pe_w, pe_w, pe_w, pe_w, pe_w, pe_w};
    wtrans_k<<<dim3(16, 24, 1), dim3(32, 8), 0, stream>>>(ppe, pe_wt, 768, 512, 0);
    TP6 ppx = {px_w, px_w, px_w, px_w, px_w, px_w};
    wtrans_k<<<dim3(24, 16, 1), dim3(32, 8), 0, stream>>>(ppx, px_wt, 512, 768, 0);
  }

  // ---- patch embed ----
  pembed_k<<<4096, 256, 0, stream>>>(video, pe_ln1g, pe_ln1b, xpe);
  mgemm(stream, xpe, pe_wt, pe_b, nullptr, lnb, M, 512, 768, false);
  ln512_k<<<4096, 256, 0, stream>>>(lnb, pe_ln2g, pe_ln2b, x);

  // ---- CPB bias ----
  cpb_k<<<961, 64, 0, stream>>>(cpb_w1, cpb_b1, cpb_w2, cpb_b2, table);
  cpbexpand_k<<<256, 256, 0, stream>>>(table, biasf);

  // ---- encoder spatial (2 layers) ----
  for (int d = 0; d < 2; ++d) {
    const int li = 0 * 2 + d;
    ln512_k<<<4096, 256, 0, stream>>>(x, es_ln1g + d * 512, es_ln1b + d * 512, lnb);
    mgemm(stream, lnb, qkv_wt + (size_t)li * 786432, nullptr, nullptr, qkvb, M, 1536, 512, false);
    qk_k<<<dim3(4, 4, 128), 256, 0, stream>>>(qkvb, biasf, scr);
    softmax_k<<<8192, 256, 0, stream>>>(scr);
    pv_k<<<dim3(1, 4, 128), 256, 0, stream>>>(scr, qkvb, attn);
    mgemm(stream, attn, wo_wt + (size_t)li * 262144, nullptr, x, x, M, 512, 512, false);
    ln512_k<<<4096, 256, 0, stream>>>(x, es_ln2g + d * 512, es_ln2b + d * 512, lnb);
    mgemm(stream, lnb, w1_wt + (size_t)li * 1048576, es_b1 + d * 2048, nullptr, scr, M, 2048, 512, true);
    mgemm(stream, scr, w2_wt + (size_t)li * 1048576, es_b2 + d * 512, x, x, M, 512, 2048, false);
  }

  // ---- encoder temporal (2 layers) ----
  xpose_fwd_k<<<4096, 128, 0, stream>>>(x, tmb);
  for (int d = 0; d < 2; ++d) {
    const int li = 1 * 2 + d;
    ln512_k<<<4096, 256, 0, stream>>>(tmb, et_ln1g + d * 512, et_ln1b + d * 512, lnb);
    mgemm(stream, lnb, qkv_wt + (size_t)li * 786432, nullptr, nullptr, qkvb, M, 1536, 512, false);
    tattn_k<<<4096, 256, 0, stream>>>(qkvb, attn);
    mgemm(stream, attn, wo_wt + (size_t)li * 262144, nullptr, tmb, tmb, M, 512, 512, false);
    ln512_k<<<4096, 256, 0, stream>>>(tmb, et_ln2g + d * 512, et_ln2b + d * 512, lnb);
    mgemm(stream, lnb, w1_wt + (size_t)li * 1048576, et_b1 + d * 2048, nullptr, scr, M, 2048, 512, true);
    mgemm(stream, scr, w2_wt + (size_t)li * 1048576, et_b2 + d * 512, tmb, tmb, M, 512, 2048, false);
  }
  xpose_bwd_k<<<4096, 128, 0, stream>>>(tmb, x);

  // ---- NSVQ bottleneck ----
  featmean_k<<<8, 256, 0, stream>>>(x, feat);
  vecmat_k<<<8, 256, 0, stream>>>(feat, 512, vq_inw, 256, 0, vq_inb, zbuf, 256, 512, 256);
  vqargmin_k<<<8, 256, 0, stream>>>(zbuf, codebook, errb);
  zq_k<<<8, 256, 0, stream>>>(zbuf, noise, errb, zqb);
  vecmat_k<<<8, 256, 0, stream>>>(zqb, 256, vq_outw, 512, 0, vq_outb, act, 512, 256, 512);

  // ---- decoder (2 layers) ----
  for (int d = 0; d < 2; ++d) {
    const int li = 2 * 2 + d;
    ln512_k<<<4096, 256, 0, stream>>>(x, ds_ln1g + d * 512, ds_ln1b + d * 512, lnb);
    mgemm(stream, lnb, qkv_wt + (size_t)li * 786432, nullptr, nullptr, qkvb, M, 1536, 512, false);
    qk_k<<<dim3(4, 4, 128), 256, 0, stream>>>(qkvb, biasf, scr);
    softmax_k<<<8192, 256, 0, stream>>>(scr);
    pv_k<<<dim3(1, 4, 128), 256, 0, stream>>>(scr, qkvb, attn);
    mgemm(stream, attn, wo_wt + (size_t)li * 262144, nullptr, x, x, M, 512, 512, false);
    // cross-attn: L=1 -> softmax==1 -> out = (ctx @ wkv_v) @ cwo, broadcast over sequence
    vecmat_k<<<8, 256, 0, stream>>>(act, 512, ds_wkv + (size_t)d * 512 * 1024, 1024, 512, nullptr, vctx, 512, 512, 512);
    vecmat_k<<<8, 256, 0, stream>>>(vctx, 512, ds_cwo + (size_t)d * 512 * 512, 512, 0, nullptr, ubuf, 512, 512, 512);
    bcastadd_k<<<4096, 128, 0, stream>>>(x, ubuf);
    ln512_k<<<4096, 256, 0, stream>>>(x, ds_ln2g + d * 512, ds_ln2b + d * 512, lnb);
    mgemm(stream, lnb, w1_wt + (size_t)li * 1048576, ds_b1 + d * 2048, nullptr, scr, M, 2048, 512, true);
    mgemm(stream, scr, w2_wt + (size_t)li * 1048576, ds_b2 + d * 512, x, x, M, 512, 2048, false);
  }

  // ---- pixel head + scatter ----
  mgemm(stream, x, px_wt, px_b, nullptr, xpe, M, 768, 512, false);
  scatter_k<<<4096, 256, 0, stream>>>(xpe, out);
}

// Round 5
// 1827.163 us; speedup vs baseline: 2.1279x; 1.1702x over previous
//
#include <hip/hip_runtime.h>
#include <math.h>

// ---- static dims ----
#define SCALE 0.125f

typedef unsigned short u16;
typedef short s16x8 __attribute__((ext_vector_type(8)));
typedef u16 u16x8 __attribute__((ext_vector_type(8)));
typedef float f32x4 __attribute__((ext_vector_type(4)));

// ======================= helpers =======================
__device__ __forceinline__ float wred_sum(float v) {
#pragma unroll
  for (int o = 32; o; o >>= 1) v += __shfl_xor(v, o, 64);
  return v;
}
__device__ __forceinline__ float wred_max(float v) {
#pragma unroll
  for (int o = 32; o; o >>= 1) v = fmaxf(v, __shfl_xor(v, o, 64));
  return v;
}
__device__ __forceinline__ float gelu_tanh(float x) {
  float x3 = x * x * x;
  return 0.5f * x * (1.0f + tanhf(0.7978845608028654f * (x + 0.044715f * x3)));
}
__device__ __forceinline__ u16 f2bf(float f) {
  unsigned u = __float_as_uint(f);
  return (u16)((u + 0x7fffu + ((u >> 16) & 1u)) >> 16);
}

// ======================= weight transpose + cast: dst[N][K] bf16 = src[K][N] fp32 ===========
struct TP6 { const float* s0; const float* s1; const float* s2;
             const float* s3; const float* s4; const float* s5; };

__global__ __launch_bounds__(256) void wtrans_k(TP6 p, u16* __restrict__ dst,
                                                int K, int N, size_t mstride) {
  const float* srcs[6] = {p.s0, p.s1, p.s2, p.s3, p.s4, p.s5};
  const float* src = srcs[blockIdx.z];
  u16* d = dst + (size_t)blockIdx.z * mstride;
  __shared__ float t[32][33];
  const int tx = threadIdx.x, ty = threadIdx.y;
  const int n0 = blockIdx.x * 32, k0 = blockIdx.y * 32;
#pragma unroll
  for (int i = 0; i < 4; ++i) t[ty + i * 8][tx] = src[(size_t)(k0 + ty + i * 8) * N + n0 + tx];
  __syncthreads();
#pragma unroll
  for (int i = 0; i < 4; ++i)
    d[(size_t)(n0 + ty + i * 8) * K + k0 + tx] = f2bf(t[tx][ty + i * 8]);
}

// ======================= bf16 MFMA GEMM =======================
// C[M,N] = A[M,K](fp32, cast in-kernel) @ Bt[N,K](bf16)^T  (+bias)(+gelu)(+res)
// 128x128 tile, BK=64, 256 threads (4 waves, 2x2 of 64x64), 16x16x32 MFMA.
template <bool GELU, bool BIAS, bool RES>
__global__ __launch_bounds__(256) void mgemm_k(const float* __restrict__ A,
                                               const u16* __restrict__ Bt,
                                               const float* __restrict__ bias,
                                               const float* __restrict__ res,
                                               float* __restrict__ C,
                                               int M, int N, int K) {
  __shared__ u16 As[128 * 64];
  __shared__ u16 Bs[128 * 64];
  const int tid = threadIdx.x;
  const int lane = tid & 63, wid = tid >> 6;
  const int wr = wid >> 1, wc = wid & 1;
  const int m0 = blockIdx.y * 128, n0 = blockIdx.x * 128;
  f32x4 acc[4][4];
#pragma unroll
  for (int m = 0; m < 4; ++m)
#pragma unroll
    for (int n = 0; n < 4; ++n) acc[m][n] = (f32x4){0.f, 0.f, 0.f, 0.f};

  for (int k0 = 0; k0 < K; k0 += 64) {
#pragma unroll
    for (int p = 0; p < 4; ++p) {
      const int i = p * 256 + tid;        // 1024 chunks of 8 floats
      const int r = i >> 3, c8 = i & 7;
      const float4* src = (const float4*)&A[(size_t)(m0 + r) * K + k0 + c8 * 8];
      const float4 f0 = src[0], f1 = src[1];
      u16x8 h;
      h[0] = f2bf(f0.x); h[1] = f2bf(f0.y); h[2] = f2bf(f0.z); h[3] = f2bf(f0.w);
      h[4] = f2bf(f1.x); h[5] = f2bf(f1.y); h[6] = f2bf(f1.z); h[7] = f2bf(f1.w);
      const int byte = r * 128 + ((c8 * 16) ^ ((r & 7) << 4));
      *(u16x8*)((char*)As + byte) = h;
    }
#pragma unroll
    for (int p = 0; p < 4; ++p) {
      const int i = p * 256 + tid;        // 1024 chunks of 16B
      const int r = i >> 3, c = i & 7;
      const u16x8 h = *(const u16x8*)&Bt[(size_t)(n0 + r) * K + k0 + c * 8];
      const int byte = r * 128 + ((c * 16) ^ ((r & 7) << 4));
      *(u16x8*)((char*)Bs + byte) = h;
    }
    __syncthreads();
#pragma unroll
    for (int ks = 0; ks < 2; ++ks) {
      const int kb = ks * 64 + ((lane >> 4) << 4);
      s16x8 af[4], bfr[4];
#pragma unroll
      for (int m = 0; m < 4; ++m) {
        const int r = wr * 64 + m * 16 + (lane & 15);
        af[m] = *(const s16x8*)((const char*)As + r * 128 + (kb ^ ((r & 7) << 4)));
      }
#pragma unroll
      for (int n = 0; n < 4; ++n) {
        const int r = wc * 64 + n * 16 + (lane & 15);
        bfr[n] = *(const s16x8*)((const char*)Bs + r * 128 + (kb ^ ((r & 7) << 4)));
      }
#pragma unroll
      for (int m = 0; m < 4; ++m)
#pragma unroll
        for (int n = 0; n < 4; ++n)
          acc[m][n] = __builtin_amdgcn_mfma_f32_16x16x32_bf16(af[m], bfr[n], acc[m][n], 0, 0, 0);
    }
    __syncthreads();
  }
#pragma unroll
  for (int m = 0; m < 4; ++m) {
    const int row = m0 + wr * 64 + m * 16 + ((lane >> 4) << 2);
#pragma unroll
    for (int n = 0; n < 4; ++n) {
      const int col = n0 + wc * 64 + n * 16 + (lane & 15);
      const float bs = BIAS ? bias[col] : 0.0f;
#pragma unroll
      for (int j = 0; j < 4; ++j) {
        float v = acc[m][n][j] + bs;
        if (GELU) v = gelu_tanh(v);
        if (RES) v += res[(size_t)(row + j) * N + col];
        C[(size_t)(row + j) * N + col] = v;
      }
    }
  }
}

static void mgemm(hipStream_t st, const float* A, const u16* Bt, const float* bias,
                  const float* res, float* C, int M, int N, int K, bool gelu) {
  dim3 g(N / 128, M / 128);
  if (gelu)
    mgemm_k<true, true, false><<<g, 256, 0, st>>>(A, Bt, bias, res, C, M, N, K);
  else if (bias && res)
    mgemm_k<false, true, true><<<g, 256, 0, st>>>(A, Bt, bias, res, C, M, N, K);
  else if (bias)
    mgemm_k<false, true, false><<<g, 256, 0, st>>>(A, Bt, bias, res, C, M, N, K);
  else if (res)
    mgemm_k<false, false, true><<<g, 256, 0, st>>>(A, Bt, bias, res, C, M, N, K);
  else
    mgemm_k<false, false, false><<<g, 256, 0, st>>>(A, Bt, bias, res, C, M, N, K);
}

// ======================= patch gather + LN(768) =======================
__global__ __launch_bounds__(256) void pembed_k(const float* __restrict__ video,
                                                const float* __restrict__ g,
                                                const float* __restrict__ b,
                                                float* __restrict__ xpe) {
  const int row = blockIdx.x;  // (b,t,gh,gw)
  const int gw_ = row & 15, gh_ = (row >> 4) & 15, t = (row >> 8) & 1, bb = row >> 9;
  const int tid = threadIdx.x;
  float v[3];
  float s = 0.f, ss = 0.f;
#pragma unroll
  for (int r = 0; r < 3; ++r) {
    const int e = tid + r * 256;
    const int c = e >> 8, rem = e & 255, p1 = rem >> 4, p2 = rem & 15;
    v[r] = video[((size_t)(((bb * 3 + c) * 2 + t) * 256 + gh_ * 16 + p1)) * 256 + gw_ * 16 + p2];
    s += v[r];
    ss += v[r] * v[r];
  }
  __shared__ float r1[4], r2[4];
  s = wred_sum(s);
  ss = wred_sum(ss);
  if ((tid & 63) == 0) { r1[tid >> 6] = s; r2[tid >> 6] = ss; }
  __syncthreads();
  const float S = r1[0] + r1[1] + r1[2] + r1[3];
  const float SS = r2[0] + r2[1] + r2[2] + r2[3];
  const float mean = S * (1.0f / 768.0f);
  const float var = SS * (1.0f / 768.0f) - mean * mean;
  const float inv = rsqrtf(var + 1e-5f);
  float* out = xpe + (size_t)row * 768;
#pragma unroll
  for (int r = 0; r < 3; ++r) {
    const int e = tid + r * 256;
    out[e] = (v[r] - mean) * inv * g[e] + b[e];
  }
}

// ======================= LN over 512 =======================
__global__ __launch_bounds__(256) void ln512_k(const float* __restrict__ x,
                                               const float* __restrict__ g,
                                               const float* __restrict__ b,
                                               float* __restrict__ y) {
  const int row = blockIdx.x;
  const int tid = threadIdx.x;
  const float2 v = ((const float2*)(x + (size_t)row * 512))[tid];
  float s = v.x + v.y, ss = v.x * v.x + v.y * v.y;
  __shared__ float r1[4], r2[4];
  s = wred_sum(s);
  ss = wred_sum(ss);
  if ((tid & 63) == 0) { r1[tid >> 6] = s; r2[tid >> 6] = ss; }
  __syncthreads();
  const float S = r1[0] + r1[1] + r1[2] + r1[3];
  const float SS = r2[0] + r2[1] + r2[2] + r2[3];
  const float mean = S * (1.0f / 512.0f);
  const float var = SS * (1.0f / 512.0f) - mean * mean;
  const float inv = rsqrtf(var + 1e-5f);
  const float2 gg = ((const float2*)g)[tid];
  const float2 bb = ((const float2*)b)[tid];
  float2 o;
  o.x = (v.x - mean) * inv * gg.x + bb.x;
  o.y = (v.y - mean) * inv * gg.y + bb.y;
  ((float2*)(y + (size_t)row * 512))[tid] = o;
}

// ======================= CPB table (31x31 rel positions x 8 heads) =======================
__global__ __launch_bounds__(64) void cpb_k(const float* __restrict__ w1, const float* __restrict__ b1,
                                            const float* __restrict__ w2, const float* __restrict__ b2,
                                            float* __restrict__ table) {
  const int r = blockIdx.x;  // 0..960
  const float ry = (float)(r / 31 - 15), rx = (float)(r % 31 - 15);
  const int lane = threadIdx.x;
  float o[8] = {};
  for (int k = lane; k < 512; k += 64) {
    const float h = fmaxf(ry * w1[k] + rx * w1[512 + k] + b1[k], 0.0f);
#pragma unroll
    for (int j = 0; j < 8; ++j) o[j] += h * w2[k * 8 + j];
  }
#pragma unroll
  for (int j = 0; j < 8; ++j) o[j] = wred_sum(o[j]);
  if (lane == 0)
#pragma unroll
    for (int j = 0; j < 8; ++j) table[r * 8 + j] = o[j] + b2[j];
}

__global__ __launch_bounds__(256) void cpbexpand_k(const float* __restrict__ table,
                                                   float* __restrict__ biasf) {
  const int t = blockIdx.x * 256 + threadIdx.x;  // 65536 (i,j) pairs
  const int i = t >> 8, j = t & 255;
  const int dy = (i >> 4) - (j >> 4) + 15, dx = (i & 15) - (j & 15) + 15;
  const float* e = table + (dy * 31 + dx) * 8;
#pragma unroll
  for (int h = 0; h < 8; ++h) biasf[(size_t)h * 65536 + t] = e[h];
}

// ======================= QK^T (batched, S=256, DH=64) + scale + bias =======================
__global__ __launch_bounds__(256) void qk_k(const float* __restrict__ qkv,
                                            const float* __restrict__ biasf,
                                            float* __restrict__ scores) {
  const int bh = blockIdx.z;  // n*8+h, n in [0,16)
  const int n = bh >> 3, h = bh & 7;
  const int i0 = blockIdx.y * 64, j0 = blockIdx.x * 64;
  const float* Qp = qkv + (size_t)n * 256 * 1536 + h * 64;
  const float* Kp = Qp + 512;
  __shared__ float Qs[16][68], Ks[16][68];
  const int tid = threadIdx.x;
  const int tx = tid & 15, ty = tid >> 4;
  float acc[4][4] = {};
  for (int k0 = 0; k0 < 64; k0 += 16) {
    const int rr = tid >> 4, kk = tid & 15;
#pragma unroll
    for (int r = 0; r < 4; ++r) {
      Qs[kk][rr + r * 16] = Qp[(size_t)(i0 + rr + r * 16) * 1536 + k0 + kk];
      Ks[kk][rr + r * 16] = Kp[(size_t)(j0 + rr + r * 16) * 1536 + k0 + kk];
    }
    __syncthreads();
#pragma unroll
    for (int k = 0; k < 16; ++k) {
      const float4 a4 = *(const float4*)&Qs[k][ty * 4];
      const float4 b4 = *(const float4*)&Ks[k][tx * 4];
      const float a[4] = {a4.x, a4.y, a4.z, a4.w};
      const float b[4] = {b4.x, b4.y, b4.z, b4.w};
#pragma unroll
      for (int i = 0; i < 4; ++i)
#pragma unroll
        for (int j = 0; j < 4; ++j) acc[i][j] += a[i] * b[j];
    }
    __syncthreads();
  }
  float* Cp = scores + (size_t)bh * 65536;
#pragma unroll
  for (int i = 0; i < 4; ++i) {
    const int ii = i0 + ty * 4 + i;
#pragma unroll
    for (int j = 0; j < 4; ++j) {
      const int jj = j0 + tx * 4 + j;
      Cp[(size_t)ii * 256 + jj] = acc[i][j] * SCALE + biasf[(size_t)h * 65536 + ii * 256 + jj];
    }
  }
}

// ======================= row softmax (256 wide), one wave per row =======================
__global__ __launch_bounds__(256) void softmax_k(float* __restrict__ scores) {
  const int wid = threadIdx.x >> 6, lane = threadIdx.x & 63;
  const size_t row = (size_t)blockIdx.x * 4 + wid;
  float4 v = ((float4*)(scores + row * 256))[lane];
  float m = fmaxf(fmaxf(v.x, v.y), fmaxf(v.z, v.w));
  m = wred_max(m);
  v.x = expf(v.x - m); v.y = expf(v.y - m); v.z = expf(v.z - m); v.w = expf(v.w - m);
  float s = v.x + v.y + v.z + v.w;
  s = wred_sum(s);
  const float r = 1.0f / s;
  v.x *= r; v.y *= r; v.z *= r; v.w *= r;
  ((float4*)(scores + row * 256))[lane] = v;
}

// ======================= P @ V (batched 256x64x256) =======================
__global__ __launch_bounds__(256) void pv_k(const float* __restrict__ scores,
                                            const float* __restrict__ qkv,
                                            float* __restrict__ out) {
  const int bh = blockIdx.z;
  const int n = bh >> 3, h = bh & 7;
  const int i0 = blockIdx.y * 64;
  const float* P = scores + (size_t)bh * 65536;
  const float* V = qkv + (size_t)n * 256 * 1536 + 1024 + h * 64;
  __shared__ float Ps[16][68], Vs[16][68];
  const int tid = threadIdx.x;
  const int tx = tid & 15, ty = tid >> 4;
  float acc[4][4] = {};
  for (int k0 = 0; k0 < 256; k0 += 16) {
    const int rr = tid >> 4, kk = tid & 15;
#pragma unroll
    for (int r = 0; r < 4; ++r)
      Ps[kk][rr + r * 16] = P[(size_t)(i0 + rr + r * 16) * 256 + k0 + kk];
    const int kb = tid >> 6, dd = tid & 63;
#pragma unroll
    for (int r = 0; r < 4; ++r)
      Vs[kb + r * 4][dd] = V[(size_t)(k0 + kb + r * 4) * 1536 + dd];
    __syncthreads();
#pragma unroll
    for (int k = 0; k < 16; ++k) {
      const float4 a4 = *(const float4*)&Ps[k][ty * 4];
      const float4 b4 = *(const float4*)&Vs[k][tx * 4];
      const float a[4] = {a4.x, a4.y, a4.z, a4.w};
      const float b[4] = {b4.x, b4.y, b4.z, b4.w};
#pragma unroll
      for (int i = 0; i < 4; ++i)
#pragma unroll
        for (int j = 0; j < 4; ++j) acc[i][j] += a[i] * b[j];
    }
    __syncthreads();
  }
#pragma unroll
  for (int i = 0; i < 4; ++i)
#pragma unroll
    for (int j = 0; j < 4; ++j)
      out[(size_t)(n * 256 + i0 + ty * 4 + i) * 512 + h * 64 + tx * 4 + j] = acc[i][j];
}

// ======================= temporal attention (S=2), one wave per (n,h) =======================
__global__ __launch_bounds__(256) void tattn_k(const float* __restrict__ qkv,
                                               float* __restrict__ out) {
  const int wid = threadIdx.x >> 6, lane = threadIdx.x & 63;
  const int idx = blockIdx.x * 4 + wid;  // n*8+h, n in [0,2048)
  const int n = idx >> 3, h = idx & 7;
  const float* base = qkv + (size_t)n * 2 * 1536 + h * 64;
  const float q0 = base[lane], q1 = base[1536 + lane];
  const float k0 = base[512 + lane], k1 = base[1536 + 512 + lane];
  const float v0 = base[1024 + lane], v1 = base[1536 + 1024 + lane];
  const float s00 = wred_sum(q0 * k0) * SCALE;
  const float s01 = wred_sum(q0 * k1) * SCALE;
  const float s10 = wred_sum(q1 * k0) * SCALE;
  const float s11 = wred_sum(q1 * k1) * SCALE;
  const float m0 = fmaxf(s00, s01), m1 = fmaxf(s10, s11);
  const float e00 = expf(s00 - m0), e01 = expf(s01 - m0);
  const float e10 = expf(s10 - m1), e11 = expf(s11 - m1);
  const float o0 = (e00 * v0 + e01 * v1) / (e00 + e01);
  const float o1 = (e10 * v0 + e11 * v1) / (e10 + e11);
  out[(size_t)(n * 2 + 0) * 512 + h * 64 + lane] = o0;
  out[(size_t)(n * 2 + 1) * 512 + h * 64 + lane] = o1;
}

// ======================= transposes between [B,T,HW,D] and [B,HW,T,D] =======================
__global__ __launch_bounds__(128) void xpose_fwd_k(const float* __restrict__ src, float* __restrict__ dst) {
  const int dr = blockIdx.x;  // dst row in [B*HW, T]
  const int t = dr & 1, hw = (dr >> 1) & 255, b = dr >> 9;
  const int sr = (b * 2 + t) * 256 + hw;
  ((float4*)(dst + (size_t)dr * 512))[threadIdx.x] = ((const float4*)(src + (size_t)sr * 512))[threadIdx.x];
}
__global__ __launch_bounds__(128) void xpose_bwd_k(const float* __restrict__ src, float* __restrict__ dst) {
  const int dr = blockIdx.x;  // dst row in [B*T, HW]
  const int hw = dr & 255, t = (dr >> 8) & 1, b = dr >> 9;
  const int sr = (b * 256 + hw) * 2 + t;
  ((float4*)(dst + (size_t)dr * 512))[threadIdx.x] = ((const float4*)(src + (size_t)sr * 512))[threadIdx.x];
}

// ======================= feat = mean over HW of tokens[:,1] (parallel) =======================
// grid (8, 8): b, 64-col chunk. 256 thr = 4 hw-slices of 64 rows.
__global__ __launch_bounds__(256) void featmean_k(const float* __restrict__ x, float* __restrict__ feat) {
  const int b = blockIdx.x, d0 = blockIdx.y * 64;
  const int t = threadIdx.x;
  const int d = d0 + (t & 63), sl = t >> 6;
  float s = 0.f;
#pragma unroll 8
  for (int i = 0; i < 64; ++i) {
    const int hw = sl * 64 + i;
    s += x[(size_t)((b * 2 + 1) * 256 + hw) * 512 + d];
  }
  __shared__ float red[4][64];
  red[sl][t & 63] = s;
  __syncthreads();
  if (t < 64)
    feat[b * 512 + d0 + t] = (red[0][t] + red[1][t] + red[2][t] + red[3][t]) * (1.0f / 256.0f);
}

// ======================= vec-mat, 8 rows at once: out[8][N] = A[8][K] @ W[.,coloff:] =========
// grid N/64, 256 thr = 64 cols x 4 K-slices. A staged in LDS (broadcast), W coalesced.
template <int K>
__global__ __launch_bounds__(256) void vecmat8_k(const float* __restrict__ A,
                                                 const float* __restrict__ W, int ldw, int coloff,
                                                 const float* __restrict__ bias,
                                                 float* __restrict__ out, int ldo) {
  constexpr int KS = K / 4;       // per-slice K
  constexpr int F4R = K / 4;      // float4 per A-row
  __shared__ float als[8][K];
  __shared__ float red[4][8][64];
  const int t = threadIdx.x;
  const int n0 = blockIdx.x * 64;
  // stage A [8][K]
#pragma unroll
  for (int p = 0; p < (8 * K) / 1024; ++p) {
    const int i4 = p * 256 + t;
    const int r = i4 / F4R, c4 = (i4 % F4R) * 4;
    *(float4*)&als[r][c4] = *(const float4*)&A[(size_t)r * K + c4];
  }
  __syncthreads();
  const int nl = t & 63, sl = t >> 6;
  const int kb = sl * KS;
  const float* Wp = W + (size_t)kb * ldw + coloff + n0 + nl;
  float acc[8] = {};
#pragma unroll 8
  for (int kk = 0; kk < KS; ++kk) {
    const float w = Wp[(size_t)kk * ldw];
#pragma unroll
    for (int r = 0; r < 8; ++r) acc[r] = fmaf(als[r][kb + kk], w, acc[r]);
  }
#pragma unroll
  for (int r = 0; r < 8; ++r) red[sl][r][nl] = acc[r];
  __syncthreads();
  if (t < 64) {
    const float bs = bias ? bias[n0 + t] : 0.0f;
#pragma unroll
    for (int r = 0; r < 8; ++r) {
      const float s = red[0][r][t] + red[1][r][t] + red[2][r][t] + red[3][r][t] + bs;
      out[(size_t)r * ldo + n0 + t] = s;
    }
  }
}

// ======================= VQ: argmin + err + zq in one block per b ============================
// 1024 threads = 16 waves; wave w scans codewords [w*64, w*64+64).
__global__ __launch_bounds__(1024) void vq_k(const float* __restrict__ z,
                                             const float* __restrict__ cb,
                                             const float* __restrict__ noise,
                                             float* __restrict__ zq) {
  const int b = blockIdx.x;
  const int t = threadIdx.x, lane = t & 63, wid = t >> 6;
  __shared__ float zs[256];
  __shared__ float wbd[16];
  __shared__ int wbk[16];
  __shared__ float esh, nsh;
  __shared__ int bks;
  if (t < 256) zs[t] = z[b * 256 + t];
  __syncthreads();
  const float4 zl = ((const float4*)zs)[lane];
  float bd = 3.4e38f;
  int bk = 0x7fffffff;
  for (int i = 0; i < 64; ++i) {
    const int k = wid * 64 + i;
    const float4 c4 = *(const float4*)&cb[(size_t)k * 256 + lane * 4];
    const float dx = zl.x - c4.x, dy = zl.y - c4.y, dz = zl.z - c4.z, dw = zl.w - c4.w;
    float d = dx * dx + dy * dy + dz * dz + dw * dw;
    d = wred_sum(d);
    if (d < bd) { bd = d; bk = k; }
  }
  if (lane == 0) { wbd[wid] = bd; wbk[wid] = bk; }
  __syncthreads();
  if (t == 0) {
    float best = wbd[0];
    int bi = wbk[0];
    for (int w = 1; w < 16; ++w)
      if (wbd[w] < best) { best = wbd[w]; bi = wbk[w]; }
    bks = bi;
  }
  __syncthreads();
  const int kbest = bks;
  if (wid == 0) {
    const float4 c4 = *(const float4*)&cb[(size_t)kbest * 256 + lane * 4];
    const float dx = zl.x - c4.x, dy = zl.y - c4.y, dz = zl.z - c4.z, dw = zl.w - c4.w;
    const float e2 = wred_sum(dx * dx + dy * dy + dz * dz + dw * dw);
    if (lane == 0) esh = sqrtf(e2);
  } else if (wid == 1) {
    const float4 n4 = ((const float4*)(noise + b * 256))[lane];
    const float nn = wred_sum(n4.x * n4.x + n4.y * n4.y + n4.z * n4.z + n4.w * n4.w);
    if (lane == 0) nsh = sqrtf(nn);
  }
  __syncthreads();
  if (t < 256) zq[b * 256 + t] = zs[t] + esh / (nsh + 1e-8f) * noise[b * 256 + t];
}

// ======================= cross-attn broadcast add =======================
__global__ __launch_bounds__(128) void bcastadd_k(float* __restrict__ x, const float* __restrict__ u) {
  const int row = blockIdx.x;
  const int b = row >> 9;
  float4* xr = (float4*)(x + (size_t)row * 512);
  const float4 uv = ((const float4*)(u + (size_t)b * 512))[threadIdx.x];
  float4 v = xr[threadIdx.x];
  v.x += uv.x; v.y += uv.y; v.z += uv.z; v.w += uv.w;
  xr[threadIdx.x] = v;
}

// ======================= scatter pix -> recon [B,C,T,H,W] =======================
__global__ __launch_bounds__(256) void scatter_k(const float* __restrict__ pix, float* __restrict__ out) {
  const int row = blockIdx.x;  // (b,t,gh,gw)
  const int gw_ = row & 15, gh_ = (row >> 4) & 15, t = (row >> 8) & 1, bb = row >> 9;
#pragma unroll
  for (int r = 0; r < 3; ++r) {
    const int e = threadIdx.x + r * 256;
    const int c = e >> 8, rem = e & 255, p1 = rem >> 4, p2 = rem & 15;
    out[((size_t)(((bb * 3 + c) * 2 + t) * 256 + gh_ * 16 + p1)) * 256 + gw_ * 16 + p2] =
        pix[(size_t)row * 768 + e];
  }
}

// ======================= host =======================
extern "C" void kernel_launch(void* const* d_in, const int* in_sizes, int n_in,
                              void* d_out, int out_size, void* d_ws, size_t ws_size,
                              hipStream_t stream) {
  const float* video   = (const float*)d_in[0];
  const float* pe_ln1g = (const float*)d_in[1];
  const float* pe_ln1b = (const float*)d_in[2];
  const float* pe_w    = (const float*)d_in[3];
  const float* pe_b    = (const float*)d_in[4];
  const float* pe_ln2g = (const float*)d_in[5];
  const float* pe_ln2b = (const float*)d_in[6];
  const float* cpb_w1  = (const float*)d_in[7];
  const float* cpb_b1  = (const float*)d_in[8];
  const float* cpb_w2  = (const float*)d_in[9];
  const float* cpb_b2  = (const float*)d_in[10];
  const float* es_ln1g = (const float*)d_in[11];
  const float* es_ln1b = (const float*)d_in[12];
  const float* es_wqkv = (const float*)d_in[13];
  const float* es_wo   = (const float*)d_in[14];
  const float* es_ln2g = (const float*)d_in[15];
  const float* es_ln2b = (const float*)d_in[16];
  const float* es_w1   = (const float*)d_in[17];
  const float* es_b1   = (const float*)d_in[18];
  const float* es_w2   = (const float*)d_in[19];
  const float* es_b2   = (const float*)d_in[20];
  const float* et_ln1g = (const float*)d_in[21];
  const float* et_ln1b = (const float*)d_in[22];
  const float* et_wqkv = (const float*)d_in[23];
  const float* et_wo   = (const float*)d_in[24];
  const float* et_ln2g = (const float*)d_in[25];
  const float* et_ln2b = (const float*)d_in[26];
  const float* et_w1   = (const float*)d_in[27];
  const float* et_b1   = (const float*)d_in[28];
  const float* et_w2   = (const float*)d_in[29];
  const float* et_b2   = (const float*)d_in[30];
  const float* ds_ln1g = (const float*)d_in[31];
  const float* ds_ln1b = (const float*)d_in[32];
  const float* ds_wqkv = (const float*)d_in[33];
  const float* ds_wo   = (const float*)d_in[34];
  // d_in[35..37] ds_clng/ds_clnb/ds_wq: mathematically dead (L=1 softmax == 1)
  const float* ds_wkv  = (const float*)d_in[38];
  const float* ds_cwo  = (const float*)d_in[39];
  const float* ds_ln2g = (const float*)d_in[40];
  const float* ds_ln2b = (const float*)d_in[41];
  const float* ds_w1   = (const float*)d_in[42];
  const float* ds_b1   = (const float*)d_in[43];
  const float* ds_w2   = (const float*)d_in[44];
  const float* ds_b2   = (const float*)d_in[45];
  const float* vq_inw  = (const float*)d_in[46];
  const float* vq_inb  = (const float*)d_in[47];
  const float* codebook= (const float*)d_in[48];
  const float* vq_outw = (const float*)d_in[49];
  const float* vq_outb = (const float*)d_in[50];
  const float* noise   = (const float*)d_in[51];
  const float* px_w    = (const float*)d_in[52];
  const float* px_b    = (const float*)d_in[53];
  float* out = (float*)d_out;

  // workspace layout (floats)
  float* ws = (float*)d_ws;
  float* xpe  = ws;                   // 4096*768  (also reused for pix)
  float* x    = xpe + 3145728;        // 4096*512
  float* lnb  = x + 2097152;          // 4096*512
  float* qkvb = lnb + 2097152;        // 4096*1536
  float* scr  = qkvb + 6291456;       // 8388608: scores OR ff1
  float* attn = scr + 8388608;        // 4096*512
  float* tmb  = attn + 2097152;       // 4096*512
  float* biasf= tmb + 2097152;        // 8*256*256
  float* table= biasf + 524288;       // 961*8
  float* feat = table + 7688;         // 8*512
  float* zbuf = feat + 4096;          // 8*256
  float* zqb  = zbuf + 2048;          // 8*256
  float* act  = zqb + 2048;           // 8*512
  float* vctx = act + 4096;           // 8*512
  float* ubuf = vctx + 4096;          // 8*512
  float* errb = ubuf + 4096;          // 8 (unused)
  // bf16 transposed weights (ushort), 16B-aligned tail
  u16* wbf    = (u16*)(errb + 8);
  u16* pe_wt  = wbf;                   // 512x768
  u16* qkv_wt = pe_wt + 393216;        // 6 x (1536x512)
  u16* wo_wt  = qkv_wt + 4718592;      // 6 x (512x512)
  u16* w1_wt  = wo_wt + 1572864;       // 6 x (2048x512)
  u16* w2_wt  = w1_wt + 6291456;       // 6 x (512x2048)
  u16* px_wt  = w2_wt + 6291456;       // 768x512

  const int M = 4096;

  // ---- weight cast+transpose (bf16, [N][K]) ----
  {
    TP6 pqkv = {es_wqkv, es_wqkv + 786432, et_wqkv, et_wqkv + 786432, ds_wqkv, ds_wqkv + 786432};
    wtrans_k<<<dim3(48, 16, 6), dim3(32, 8), 0, stream>>>(pqkv, qkv_wt, 512, 1536, 786432);
    TP6 pwo = {es_wo, es_wo + 262144, et_wo, et_wo + 262144, ds_wo, ds_wo + 262144};
    wtrans_k<<<dim3(16, 16, 6), dim3(32, 8), 0, stream>>>(pwo, wo_wt, 512, 512, 262144);
    TP6 pw1 = {es_w1, es_w1 + 1048576, et_w1, et_w1 + 1048576, ds_w1, ds_w1 + 1048576};
    wtrans_k<<<dim3(64, 16, 6), dim3(32, 8), 0, stream>>>(pw1, w1_wt, 512, 2048, 1048576);
    TP6 pw2 = {es_w2, es_w2 + 1048576, et_w2, et_w2 + 1048576, ds_w2, ds_w2 + 1048576};
    wtrans_k<<<dim3(16, 64, 6), dim3(32, 8), 0, stream>>>(pw2, w2_wt, 2048, 512, 1048576);
    TP6 ppe = {pe_w, pe_w, pe_w, pe_w, pe_w, pe_w};
    wtrans_k<<<dim3(16, 24, 1), dim3(32, 8), 0, stream>>>(ppe, pe_wt, 768, 512, 0);
    TP6 ppx = {px_w, px_w, px_w, px_w, px_w, px_w};
    wtrans_k<<<dim3(24, 16, 1), dim3(32, 8), 0, stream>>>(ppx, px_wt, 512, 768, 0);
  }

  // ---- patch embed ----
  pembed_k<<<4096, 256, 0, stream>>>(video, pe_ln1g, pe_ln1b, xpe);
  mgemm(stream, xpe, pe_wt, pe_b, nullptr, lnb, M, 512, 768, false);
  ln512_k<<<4096, 256, 0, stream>>>(lnb, pe_ln2g, pe_ln2b, x);

  // ---- CPB bias ----
  cpb_k<<<961, 64, 0, stream>>>(cpb_w1, cpb_b1, cpb_w2, cpb_b2, table);
  cpbexpand_k<<<256, 256, 0, stream>>>(table, biasf);

  // ---- encoder spatial (2 layers) ----
  for (int d = 0; d < 2; ++d) {
    const int li = 0 * 2 + d;
    ln512_k<<<4096, 256, 0, stream>>>(x, es_ln1g + d * 512, es_ln1b + d * 512, lnb);
    mgemm(stream, lnb, qkv_wt + (size_t)li * 786432, nullptr, nullptr, qkvb, M, 1536, 512, false);
    qk_k<<<dim3(4, 4, 128), 256, 0, stream>>>(qkvb, biasf, scr);
    softmax_k<<<8192, 256, 0, stream>>>(scr);
    pv_k<<<dim3(1, 4, 128), 256, 0, stream>>>(scr, qkvb, attn);
    mgemm(stream, attn, wo_wt + (size_t)li * 262144, nullptr, x, x, M, 512, 512, false);
    ln512_k<<<4096, 256, 0, stream>>>(x, es_ln2g + d * 512, es_ln2b + d * 512, lnb);
    mgemm(stream, lnb, w1_wt + (size_t)li * 1048576, es_b1 + d * 2048, nullptr, scr, M, 2048, 512, true);
    mgemm(stream, scr, w2_wt + (size_t)li * 1048576, es_b2 + d * 512, x, x, M, 512, 2048, false);
  }

  // ---- encoder temporal (2 layers) ----
  xpose_fwd_k<<<4096, 128, 0, stream>>>(x, tmb);
  for (int d = 0; d < 2; ++d) {
    const int li = 1 * 2 + d;
    ln512_k<<<4096, 256, 0, stream>>>(tmb, et_ln1g + d * 512, et_ln1b + d * 512, lnb);
    mgemm(stream, lnb, qkv_wt + (size_t)li * 786432, nullptr, nullptr, qkvb, M, 1536, 512, false);
    tattn_k<<<4096, 256, 0, stream>>>(qkvb, attn);
    mgemm(stream, attn, wo_wt + (size_t)li * 262144, nullptr, tmb, tmb, M, 512, 512, false);
    ln512_k<<<4096, 256, 0, stream>>>(tmb, et_ln2g + d * 512, et_ln2b + d * 512, lnb);
    mgemm(stream, lnb, w1_wt + (size_t)li * 1048576, et_b1 + d * 2048, nullptr, scr, M, 2048, 512, true);
    mgemm(stream, scr, w2_wt + (size_t)li * 1048576, et_b2 + d * 512, tmb, tmb, M, 512, 2048, false);
  }
  xpose_bwd_k<<<4096, 128, 0, stream>>>(tmb, x);

  // ---- NSVQ bottleneck ----
  featmean_k<<<dim3(8, 8), 256, 0, stream>>>(x, feat);
  vecmat8_k<512><<<4, 256, 0, stream>>>(feat, vq_inw, 256, 0, vq_inb, zbuf, 256);
  vq_k<<<8, 1024, 0, stream>>>(zbuf, codebook, noise, zqb);
  vecmat8_k<256><<<8, 256, 0, stream>>>(zqb, vq_outw, 512, 0, vq_outb, act, 512);

  // ---- decoder (2 layers) ----
  for (int d = 0; d < 2; ++d) {
    const int li = 2 * 2 + d;
    ln512_k<<<4096, 256, 0, stream>>>(x, ds_ln1g + d * 512, ds_ln1b + d * 512, lnb);
    mgemm(stream, lnb, qkv_wt + (size_t)li * 786432, nullptr, nullptr, qkvb, M, 1536, 512, false);
    qk_k<<<dim3(4, 4, 128), 256, 0, stream>>>(qkvb, biasf, scr);
    softmax_k<<<8192, 256, 0, stream>>>(scr);
    pv_k<<<dim3(1, 4, 128), 256, 0, stream>>>(scr, qkvb, attn);
    mgemm(stream, attn, wo_wt + (size_t)li * 262144, nullptr, x, x, M, 512, 512, false);
    // cross-attn: L=1 -> softmax==1 -> out = (ctx @ wkv_v) @ cwo, broadcast over sequence
    vecmat8_k<512><<<8, 256, 0, stream>>>(act, ds_wkv + (size_t)d * 512 * 1024, 1024, 512, nullptr, vctx, 512);
    vecmat8_k<512><<<8, 256, 0, stream>>>(vctx, ds_cwo + (size_t)d * 512 * 512, 512, 0, nullptr, ubuf, 512);
    bcastadd_k<<<4096, 128, 0, stream>>>(x, ubuf);
    ln512_k<<<4096, 256, 0, stream>>>(x, ds_ln2g + d * 512, ds_ln2b + d * 512, lnb);
    mgemm(stream, lnb, w1_wt + (size_t)li * 1048576, ds_b1 + d * 2048, nullptr, scr, M, 2048, 512, true);
    mgemm(stream, scr, w2_wt + (size_t)li * 1048576, ds_b2 + d * 512, x, x, M, 512, 2048, false);
  }

  // ---- pixel head + scatter ----
  mgemm(stream, x, px_wt, px_b, nullptr, xpe, M, 768, 512, false);
  scatter_k<<<4096, 256, 0, stream>>>(xpe, out);
}

// Round 8
// 1712.550 us; speedup vs baseline: 2.2703x; 1.0669x over previous
//
#include <hip/hip_runtime.h>
#include <math.h>

// ---- static dims ----
#define SCALE 0.125f

typedef unsigned short u16;
typedef short s16x8 __attribute__((ext_vector_type(8)));
typedef u16 u16x8 __attribute__((ext_vector_type(8)));
typedef float f32x4 __attribute__((ext_vector_type(4)));

// ======================= helpers =======================
__device__ __forceinline__ float wred_sum(float v) {
#pragma unroll
  for (int o = 32; o; o >>= 1) v += __shfl_xor(v, o, 64);
  return v;
}
__device__ __forceinline__ float wred_max(float v) {
#pragma unroll
  for (int o = 32; o; o >>= 1) v = fmaxf(v, __shfl_xor(v, o, 64));
  return v;
}
__device__ __forceinline__ float gelu_tanh(float x) {
  float x3 = x * x * x;
  return 0.5f * x * (1.0f + tanhf(0.7978845608028654f * (x + 0.044715f * x3)));
}
__device__ __forceinline__ u16 f2bf(float f) {
  unsigned u = __float_as_uint(f);
  return (u16)((u + 0x7fffu + ((u >> 16) & 1u)) >> 16);
}

// ======================= weight transpose + cast: dst[N][K] bf16 = src[K][N] fp32 ===========
struct TP6 { const float* s0; const float* s1; const float* s2;
             const float* s3; const float* s4; const float* s5; };

__global__ __launch_bounds__(256) void wtrans_k(TP6 p, u16* __restrict__ dst,
                                                int K, int N, size_t mstride) {
  const float* srcs[6] = {p.s0, p.s1, p.s2, p.s3, p.s4, p.s5};
  const float* src = srcs[blockIdx.z];
  u16* d = dst + (size_t)blockIdx.z * mstride;
  __shared__ float t[32][33];
  const int tx = threadIdx.x, ty = threadIdx.y;
  const int n0 = blockIdx.x * 32, k0 = blockIdx.y * 32;
#pragma unroll
  for (int i = 0; i < 4; ++i) t[ty + i * 8][tx] = src[(size_t)(k0 + ty + i * 8) * N + n0 + tx];
  __syncthreads();
#pragma unroll
  for (int i = 0; i < 4; ++i)
    d[(size_t)(n0 + ty + i * 8) * K + k0 + tx] = f2bf(t[tx][ty + i * 8]);
}

// ======================= bf16 MFMA GEMM =======================
// C[M,N] = A[M,K](fp32, cast in-kernel) @ Bt[N,K](bf16)^T  (+bias)(+gelu)(+res)
// 64x64 tile, BK=64, 256 threads (4 waves, 2x2 of 32x32), 16x16x32 MFMA.
// 1D grid with XCD-chunked swizzle (nwg % 8 == 0): same-A-stripe blocks stay on one XCD.
template <bool GELU, bool BIAS, bool RES>
__global__ __launch_bounds__(256) void mgemm_k(const float* __restrict__ A,
                                               const u16* __restrict__ Bt,
                                               const float* __restrict__ bias,
                                               const float* __restrict__ res,
                                               float* __restrict__ C,
                                               int M, int N, int K, int nx, int chunk) {
  __shared__ u16 As[64 * 64];
  __shared__ u16 Bs[64 * 64];
  const int tid = threadIdx.x;
  const int lane = tid & 63, wid = tid >> 6;
  const int wr = wid >> 1, wc = wid & 1;
  const int bid = blockIdx.x;
  const int lt = (bid & 7) * chunk + (bid >> 3);   // XCD-chunked logical tile
  const int ty = lt / nx, tx = lt - ty * nx;
  const int m0 = ty * 64, n0 = tx * 64;
  f32x4 acc[2][2];
#pragma unroll
  for (int m = 0; m < 2; ++m)
#pragma unroll
    for (int n = 0; n < 2; ++n) acc[m][n] = (f32x4){0.f, 0.f, 0.f, 0.f};

  for (int k0 = 0; k0 < K; k0 += 64) {
    // ---- stage A: 64 rows x 64 k, fp32 -> bf16, XOR-swizzled 16B slots ----
#pragma unroll
    for (int p = 0; p < 2; ++p) {
      const int i = p * 256 + tid;        // 512 chunks of 8 floats
      const int r = i >> 3, c8 = i & 7;
      const float4* src = (const float4*)&A[(size_t)(m0 + r) * K + k0 + c8 * 8];
      const float4 f0 = src[0], f1 = src[1];
      u16x8 h;
      h[0] = f2bf(f0.x); h[1] = f2bf(f0.y); h[2] = f2bf(f0.z); h[3] = f2bf(f0.w);
      h[4] = f2bf(f1.x); h[5] = f2bf(f1.y); h[6] = f2bf(f1.z); h[7] = f2bf(f1.w);
      const int byte = r * 128 + ((c8 * 16) ^ ((r & 7) << 4));
      *(u16x8*)((char*)As + byte) = h;
    }
    // ---- stage B: 64 n-rows x 64 k bf16 from Bt, swizzled ----
#pragma unroll
    for (int p = 0; p < 2; ++p) {
      const int i = p * 256 + tid;        // 512 chunks of 16B
      const int r = i >> 3, c = i & 7;
      const u16x8 h = *(const u16x8*)&Bt[(size_t)(n0 + r) * K + k0 + c * 8];
      const int byte = r * 128 + ((c * 16) ^ ((r & 7) << 4));
      *(u16x8*)((char*)Bs + byte) = h;
    }
    __syncthreads();
#pragma unroll
    for (int ks = 0; ks < 2; ++ks) {
      const int kb = ks * 64 + ((lane >> 4) << 4);  // byte offset of this lane's 8 bf16
      s16x8 af[2], bfr[2];
#pragma unroll
      for (int m = 0; m < 2; ++m) {
        const int r = wr * 32 + m * 16 + (lane & 15);
        af[m] = *(const s16x8*)((const char*)As + r * 128 + (kb ^ ((r & 7) << 4)));
      }
#pragma unroll
      for (int n = 0; n < 2; ++n) {
        const int r = wc * 32 + n * 16 + (lane & 15);
        bfr[n] = *(const s16x8*)((const char*)Bs + r * 128 + (kb ^ ((r & 7) << 4)));
      }
#pragma unroll
      for (int m = 0; m < 2; ++m)
#pragma unroll
        for (int n = 0; n < 2; ++n)
          acc[m][n] = __builtin_amdgcn_mfma_f32_16x16x32_bf16(af[m], bfr[n], acc[m][n], 0, 0, 0);
    }
    __syncthreads();
  }
  // ---- epilogue: C/D layout col=lane&15, row=(lane>>4)*4+j ----
#pragma unroll
  for (int m = 0; m < 2; ++m) {
    const int row = m0 + wr * 32 + m * 16 + ((lane >> 4) << 2);
#pragma unroll
    for (int n = 0; n < 2; ++n) {
      const int col = n0 + wc * 32 + n * 16 + (lane & 15);
      const float bs = BIAS ? bias[col] : 0.0f;
#pragma unroll
      for (int j = 0; j < 4; ++j) {
        float v = acc[m][n][j] + bs;
        if (GELU) v = gelu_tanh(v);
        if (RES) v += res[(size_t)(row + j) * N + col];
        C[(size_t)(row + j) * N + col] = v;
      }
    }
  }
}

static void mgemm(hipStream_t st, const float* A, const u16* Bt, const float* bias,
                  const float* res, float* C, int M, int N, int K, bool gelu) {
  const int nx = N / 64, nwg = nx * (M / 64), chunk = nwg / 8;
  if (gelu)
    mgemm_k<true, true, false><<<nwg, 256, 0, st>>>(A, Bt, bias, res, C, M, N, K, nx, chunk);
  else if (bias && res)
    mgemm_k<false, true, true><<<nwg, 256, 0, st>>>(A, Bt, bias, res, C, M, N, K, nx, chunk);
  else if (bias)
    mgemm_k<false, true, false><<<nwg, 256, 0, st>>>(A, Bt, bias, res, C, M, N, K, nx, chunk);
  else if (res)
    mgemm_k<false, false, true><<<nwg, 256, 0, st>>>(A, Bt, bias, res, C, M, N, K, nx, chunk);
  else
    mgemm_k<false, false, false><<<nwg, 256, 0, st>>>(A, Bt, bias, res, C, M, N, K, nx, chunk);
}

// ======================= patch gather + LN(768) =======================
__global__ __launch_bounds__(256) void pembed_k(const float* __restrict__ video,
                                                const float* __restrict__ g,
                                                const float* __restrict__ b,
                                                float* __restrict__ xpe) {
  const int row = blockIdx.x;  // (b,t,gh,gw)
  const int gw_ = row & 15, gh_ = (row >> 4) & 15, t = (row >> 8) & 1, bb = row >> 9;
  const int tid = threadIdx.x;
  float v[3];
  float s = 0.f, ss = 0.f;
#pragma unroll
  for (int r = 0; r < 3; ++r) {
    const int e = tid + r * 256;
    const int c = e >> 8, rem = e & 255, p1 = rem >> 4, p2 = rem & 15;
    v[r] = video[((size_t)(((bb * 3 + c) * 2 + t) * 256 + gh_ * 16 + p1)) * 256 + gw_ * 16 + p2];
    s += v[r];
    ss += v[r] * v[r];
  }
  __shared__ float r1[4], r2[4];
  s = wred_sum(s);
  ss = wred_sum(ss);
  if ((tid & 63) == 0) { r1[tid >> 6] = s; r2[tid >> 6] = ss; }
  __syncthreads();
  const float S = r1[0] + r1[1] + r1[2] + r1[3];
  const float SS = r2[0] + r2[1] + r2[2] + r2[3];
  const float mean = S * (1.0f / 768.0f);
  const float var = SS * (1.0f / 768.0f) - mean * mean;
  const float inv = rsqrtf(var + 1e-5f);
  float* out = xpe + (size_t)row * 768;
#pragma unroll
  for (int r = 0; r < 3; ++r) {
    const int e = tid + r * 256;
    out[e] = (v[r] - mean) * inv * g[e] + b[e];
  }
}

// ======================= LN over 512 =======================
__global__ __launch_bounds__(256) void ln512_k(const float* __restrict__ x,
                                               const float* __restrict__ g,
                                               const float* __restrict__ b,
                                               float* __restrict__ y) {
  const int row = blockIdx.x;
  const int tid = threadIdx.x;
  const float2 v = ((const float2*)(x + (size_t)row * 512))[tid];
  float s = v.x + v.y, ss = v.x * v.x + v.y * v.y;
  __shared__ float r1[4], r2[4];
  s = wred_sum(s);
  ss = wred_sum(ss);
  if ((tid & 63) == 0) { r1[tid >> 6] = s; r2[tid >> 6] = ss; }
  __syncthreads();
  const float S = r1[0] + r1[1] + r1[2] + r1[3];
  const float SS = r2[0] + r2[1] + r2[2] + r2[3];
  const float mean = S * (1.0f / 512.0f);
  const float var = SS * (1.0f / 512.0f) - mean * mean;
  const float inv = rsqrtf(var + 1e-5f);
  const float2 gg = ((const float2*)g)[tid];
  const float2 bb = ((const float2*)b)[tid];
  float2 o;
  o.x = (v.x - mean) * inv * gg.x + bb.x;
  o.y = (v.y - mean) * inv * gg.y + bb.y;
  ((float2*)(y + (size_t)row * 512))[tid] = o;
}

// ======================= CPB table (31x31 rel positions x 8 heads) =======================
__global__ __launch_bounds__(64) void cpb_k(const float* __restrict__ w1, const float* __restrict__ b1,
                                            const float* __restrict__ w2, const float* __restrict__ b2,
                                            float* __restrict__ table) {
  const int r = blockIdx.x;  // 0..960
  const float ry = (float)(r / 31 - 15), rx = (float)(r % 31 - 15);
  const int lane = threadIdx.x;
  float o[8] = {};
  for (int k = lane; k < 512; k += 64) {
    const float h = fmaxf(ry * w1[k] + rx * w1[512 + k] + b1[k], 0.0f);
#pragma unroll
    for (int j = 0; j < 8; ++j) o[j] += h * w2[k * 8 + j];
  }
#pragma unroll
  for (int j = 0; j < 8; ++j) o[j] = wred_sum(o[j]);
  if (lane == 0)
#pragma unroll
    for (int j = 0; j < 8; ++j) table[r * 8 + j] = o[j] + b2[j];
}

__global__ __launch_bounds__(256) void cpbexpand_k(const float* __restrict__ table,
                                                   float* __restrict__ biasf) {
  const int t = blockIdx.x * 256 + threadIdx.x;  // 65536 (i,j) pairs
  const int i = t >> 8, j = t & 255;
  const int dy = (i >> 4) - (j >> 4) + 15, dx = (i & 15) - (j & 15) + 15;
  const float* e = table + (dy * 31 + dx) * 8;
#pragma unroll
  for (int h = 0; h < 8; ++h) biasf[(size_t)h * 65536 + t] = e[h];
}

// ======================= QK^T (batched, S=256, DH=64) + scale + bias =======================
__global__ __launch_bounds__(256) void qk_k(const float* __restrict__ qkv,
                                            const float* __restrict__ biasf,
                                            float* __restrict__ scores) {
  const int bh = blockIdx.z;  // n*8+h, n in [0,16)
  const int n = bh >> 3, h = bh & 7;
  const int i0 = blockIdx.y * 64, j0 = blockIdx.x * 64;
  const float* Qp = qkv + (size_t)n * 256 * 1536 + h * 64;
  const float* Kp = Qp + 512;
  __shared__ float Qs[16][68], Ks[16][68];
  const int tid = threadIdx.x;
  const int tx = tid & 15, ty = tid >> 4;
  float acc[4][4] = {};
  for (int k0 = 0; k0 < 64; k0 += 16) {
    const int rr = tid >> 4, kk = tid & 15;
#pragma unroll
    for (int r = 0; r < 4; ++r) {
      Qs[kk][rr + r * 16] = Qp[(size_t)(i0 + rr + r * 16) * 1536 + k0 + kk];
      Ks[kk][rr + r * 16] = Kp[(size_t)(j0 + rr + r * 16) * 1536 + k0 + kk];
    }
    __syncthreads();
#pragma unroll
    for (int k = 0; k < 16; ++k) {
      const float4 a4 = *(const float4*)&Qs[k][ty * 4];
      const float4 b4 = *(const float4*)&Ks[k][tx * 4];
      const float a[4] = {a4.x, a4.y, a4.z, a4.w};
      const float b[4] = {b4.x, b4.y, b4.z, b4.w};
#pragma unroll
      for (int i = 0; i < 4; ++i)
#pragma unroll
        for (int j = 0; j < 4; ++j) acc[i][j] += a[i] * b[j];
    }
    __syncthreads();
  }
  float* Cp = scores + (size_t)bh * 65536;
#pragma unroll
  for (int i = 0; i < 4; ++i) {
    const int ii = i0 + ty * 4 + i;
#pragma unroll
    for (int j = 0; j < 4; ++j) {
      const int jj = j0 + tx * 4 + j;
      Cp[(size_t)ii * 256 + jj] = acc[i][j] * SCALE + biasf[(size_t)h * 65536 + ii * 256 + jj];
    }
  }
}

// ======================= row softmax (256 wide), one wave per row =======================
__global__ __launch_bounds__(256) void softmax_k(float* __restrict__ scores) {
  const int wid = threadIdx.x >> 6, lane = threadIdx.x & 63;
  const size_t row = (size_t)blockIdx.x * 4 + wid;
  float4 v = ((float4*)(scores + row * 256))[lane];
  float m = fmaxf(fmaxf(v.x, v.y), fmaxf(v.z, v.w));
  m = wred_max(m);
  v.x = expf(v.x - m); v.y = expf(v.y - m); v.z = expf(v.z - m); v.w = expf(v.w - m);
  float s = v.x + v.y + v.z + v.w;
  s = wred_sum(s);
  const float r = 1.0f / s;
  v.x *= r; v.y *= r; v.z *= r; v.w *= r;
  ((float4*)(scores + row * 256))[lane] = v;
}

// ======================= P @ V (batched 256x64x256) =======================
__global__ __launch_bounds__(256) void pv_k(const float* __restrict__ scores,
                                            const float* __restrict__ qkv,
                                            float* __restrict__ out) {
  const int bh = blockIdx.z;
  const int n = bh >> 3, h = bh & 7;
  const int i0 = blockIdx.y * 64;
  const float* P = scores + (size_t)bh * 65536;
  const float* V = qkv + (size_t)n * 256 * 1536 + 1024 + h * 64;
  __shared__ float Ps[16][68], Vs[16][68];
  const int tid = threadIdx.x;
  const int tx = tid & 15, ty = tid >> 4;
  float acc[4][4] = {};
  for (int k0 = 0; k0 < 256; k0 += 16) {
    const int rr = tid >> 4, kk = tid & 15;
#pragma unroll
    for (int r = 0; r < 4; ++r)
      Ps[kk][rr + r * 16] = P[(size_t)(i0 + rr + r * 16) * 256 + k0 + kk];
    const int kb = tid >> 6, dd = tid & 63;
#pragma unroll
    for (int r = 0; r < 4; ++r)
      Vs[kb + r * 4][dd] = V[(size_t)(k0 + kb + r * 4) * 1536 + dd];
    __syncthreads();
#pragma unroll
    for (int k = 0; k < 16; ++k) {
      const float4 a4 = *(const float4*)&Ps[k][ty * 4];
      const float4 b4 = *(const float4*)&Vs[k][tx * 4];
      const float a[4] = {a4.x, a4.y, a4.z, a4.w};
      const float b[4] = {b4.x, b4.y, b4.z, b4.w};
#pragma unroll
      for (int i = 0; i < 4; ++i)
#pragma unroll
        for (int j = 0; j < 4; ++j) acc[i][j] += a[i] * b[j];
    }
    __syncthreads();
  }
#pragma unroll
  for (int i = 0; i < 4; ++i)
#pragma unroll
    for (int j = 0; j < 4; ++j)
      out[(size_t)(n * 256 + i0 + ty * 4 + i) * 512 + h * 64 + tx * 4 + j] = acc[i][j];
}

// ======================= temporal attention (S=2), one wave per (n,h) =======================
__global__ __launch_bounds__(256) void tattn_k(const float* __restrict__ qkv,
                                               float* __restrict__ out) {
  const int wid = threadIdx.x >> 6, lane = threadIdx.x & 63;
  const int idx = blockIdx.x * 4 + wid;  // n*8+h, n in [0,2048)
  const int n = idx >> 3, h = idx & 7;
  const float* base = qkv + (size_t)n * 2 * 1536 + h * 64;
  const float q0 = base[lane], q1 = base[1536 + lane];
  const float k0 = base[512 + lane], k1 = base[1536 + 512 + lane];
  const float v0 = base[1024 + lane], v1 = base[1536 + 1024 + lane];
  const float s00 = wred_sum(q0 * k0) * SCALE;
  const float s01 = wred_sum(q0 * k1) * SCALE;
  const float s10 = wred_sum(q1 * k0) * SCALE;
  const float s11 = wred_sum(q1 * k1) * SCALE;
  const float m0 = fmaxf(s00, s01), m1 = fmaxf(s10, s11);
  const float e00 = expf(s00 - m0), e01 = expf(s01 - m0);
  const float e10 = expf(s10 - m1), e11 = expf(s11 - m1);
  const float o0 = (e00 * v0 + e01 * v1) / (e00 + e01);
  const float o1 = (e10 * v0 + e11 * v1) / (e10 + e11);
  out[(size_t)(n * 2 + 0) * 512 + h * 64 + lane] = o0;
  out[(size_t)(n * 2 + 1) * 512 + h * 64 + lane] = o1;
}

// ======================= transposes between [B,T,HW,D] and [B,HW,T,D] =======================
__global__ __launch_bounds__(128) void xpose_fwd_k(const float* __restrict__ src, float* __restrict__ dst) {
  const int dr = blockIdx.x;  // dst row in [B*HW, T]
  const int t = dr & 1, hw = (dr >> 1) & 255, b = dr >> 9;
  const int sr = (b * 2 + t) * 256 + hw;
  ((float4*)(dst + (size_t)dr * 512))[threadIdx.x] = ((const float4*)(src + (size_t)sr * 512))[threadIdx.x];
}
__global__ __launch_bounds__(128) void xpose_bwd_k(const float* __restrict__ src, float* __restrict__ dst) {
  const int dr = blockIdx.x;  // dst row in [B*T, HW]
  const int hw = dr & 255, t = (dr >> 8) & 1, b = dr >> 9;
  const int sr = (b * 256 + hw) * 2 + t;
  ((float4*)(dst + (size_t)dr * 512))[threadIdx.x] = ((const float4*)(src + (size_t)sr * 512))[threadIdx.x];
}

// ======================= feat = mean over HW of tokens[:,1] (parallel) =======================
__global__ __launch_bounds__(256) void featmean_k(const float* __restrict__ x, float* __restrict__ feat) {
  const int b = blockIdx.x, d0 = blockIdx.y * 64;
  const int t = threadIdx.x;
  const int d = d0 + (t & 63), sl = t >> 6;
  float s = 0.f;
#pragma unroll 8
  for (int i = 0; i < 64; ++i) {
    const int hw = sl * 64 + i;
    s += x[(size_t)((b * 2 + 1) * 256 + hw) * 512 + d];
  }
  __shared__ float red[4][64];
  red[sl][t & 63] = s;
  __syncthreads();
  if (t < 64)
    feat[b * 512 + d0 + t] = (red[0][t] + red[1][t] + red[2][t] + red[3][t]) * (1.0f / 256.0f);
}

// ======================= vec-mat, 8 rows at once =======================
template <int K>
__global__ __launch_bounds__(256) void vecmat8_k(const float* __restrict__ A,
                                                 const float* __restrict__ W, int ldw, int coloff,
                                                 const float* __restrict__ bias,
                                                 float* __restrict__ out, int ldo) {
  constexpr int KS = K / 4;       // per-slice K
  constexpr int F4R = K / 4;      // float4 per A-row
  __shared__ float als[8][K];
  __shared__ float red[4][8][64];
  const int t = threadIdx.x;
  const int n0 = blockIdx.x * 64;
#pragma unroll
  for (int p = 0; p < (8 * K) / 1024; ++p) {
    const int i4 = p * 256 + t;
    const int r = i4 / F4R, c4 = (i4 % F4R) * 4;
    *(float4*)&als[r][c4] = *(const float4*)&A[(size_t)r * K + c4];
  }
  __syncthreads();
  const int nl = t & 63, sl = t >> 6;
  const int kb = sl * KS;
  const float* Wp = W + (size_t)kb * ldw + coloff + n0 + nl;
  float acc[8] = {};
#pragma unroll 8
  for (int kk = 0; kk < KS; ++kk) {
    const float w = Wp[(size_t)kk * ldw];
#pragma unroll
    for (int r = 0; r < 8; ++r) acc[r] = fmaf(als[r][kb + kk], w, acc[r]);
  }
#pragma unroll
  for (int r = 0; r < 8; ++r) red[sl][r][nl] = acc[r];
  __syncthreads();
  if (t < 64) {
    const float bs = bias ? bias[n0 + t] : 0.0f;
#pragma unroll
    for (int r = 0; r < 8; ++r) {
      const float s = red[0][r][t] + red[1][r][t] + red[2][r][t] + red[3][r][t] + bs;
      out[(size_t)r * ldo + n0 + t] = s;
    }
  }
}

// ======================= VQ: argmin + err + zq in one block per b ============================
__global__ __launch_bounds__(1024) void vq_k(const float* __restrict__ z,
                                             const float* __restrict__ cb,
                                             const float* __restrict__ noise,
                                             float* __restrict__ zq) {
  const int b = blockIdx.x;
  const int t = threadIdx.x, lane = t & 63, wid = t >> 6;
  __shared__ float zs[256];
  __shared__ float wbd[16];
  __shared__ int wbk[16];
  __shared__ float esh, nsh;
  __shared__ int bks;
  if (t < 256) zs[t] = z[b * 256 + t];
  __syncthreads();
  const float4 zl = ((const float4*)zs)[lane];
  float bd = 3.4e38f;
  int bk = 0x7fffffff;
  for (int i = 0; i < 64; ++i) {
    const int k = wid * 64 + i;
    const float4 c4 = *(const float4*)&cb[(size_t)k * 256 + lane * 4];
    const float dx = zl.x - c4.x, dy = zl.y - c4.y, dz = zl.z - c4.z, dw = zl.w - c4.w;
    float d = dx * dx + dy * dy + dz * dz + dw * dw;
    d = wred_sum(d);
    if (d < bd) { bd = d; bk = k; }
  }
  if (lane == 0) { wbd[wid] = bd; wbk[wid] = bk; }
  __syncthreads();
  if (t == 0) {
    float best = wbd[0];
    int bi = wbk[0];
    for (int w = 1; w < 16; ++w)
      if (wbd[w] < best) { best = wbd[w]; bi = wbk[w]; }
    bks = bi;
  }
  __syncthreads();
  const int kbest = bks;
  if (wid == 0) {
    const float4 c4 = *(const float4*)&cb[(size_t)kbest * 256 + lane * 4];
    const float dx = zl.x - c4.x, dy = zl.y - c4.y, dz = zl.z - c4.z, dw = zl.w - c4.w;
    const float e2 = wred_sum(dx * dx + dy * dy + dz * dz + dw * dw);
    if (lane == 0) esh = sqrtf(e2);
  } else if (wid == 1) {
    const float4 n4 = ((const float4*)(noise + b * 256))[lane];
    const float nn = wred_sum(n4.x * n4.x + n4.y * n4.y + n4.z * n4.z + n4.w * n4.w);
    if (lane == 0) nsh = sqrtf(nn);
  }
  __syncthreads();
  if (t < 256) zq[b * 256 + t] = zs[t] + esh / (nsh + 1e-8f) * noise[b * 256 + t];
}

// ======================= cross-attn broadcast add =======================
__global__ __launch_bounds__(128) void bcastadd_k(float* __restrict__ x, const float* __restrict__ u) {
  const int row = blockIdx.x;
  const int b = row >> 9;
  float4* xr = (float4*)(x + (size_t)row * 512);
  const float4 uv = ((const float4*)(u + (size_t)b * 512))[threadIdx.x];
  float4 v = xr[threadIdx.x];
  v.x += uv.x; v.y += uv.y; v.z += uv.z; v.w += uv.w;
  xr[threadIdx.x] = v;
}

// ======================= scatter pix -> recon [B,C,T,H,W] =======================
__global__ __launch_bounds__(256) void scatter_k(const float* __restrict__ pix, float* __restrict__ out) {
  const int row = blockIdx.x;  // (b,t,gh,gw)
  const int gw_ = row & 15, gh_ = (row >> 4) & 15, t = (row >> 8) & 1, bb = row >> 9;
#pragma unroll
  for (int r = 0; r < 3; ++r) {
    const int e = threadIdx.x + r * 256;
    const int c = e >> 8, rem = e & 255, p1 = rem >> 4, p2 = rem & 15;
    out[((size_t)(((bb * 3 + c) * 2 + t) * 256 + gh_ * 16 + p1)) * 256 + gw_ * 16 + p2] =
        pix[(size_t)row * 768 + e];
  }
}

// ======================= host =======================
extern "C" void kernel_launch(void* const* d_in, const int* in_sizes, int n_in,
                              void* d_out, int out_size, void* d_ws, size_t ws_size,
                              hipStream_t stream) {
  const float* video   = (const float*)d_in[0];
  const float* pe_ln1g = (const float*)d_in[1];
  const float* pe_ln1b = (const float*)d_in[2];
  const float* pe_w    = (const float*)d_in[3];
  const float* pe_b    = (const float*)d_in[4];
  const float* pe_ln2g = (const float*)d_in[5];
  const float* pe_ln2b = (const float*)d_in[6];
  const float* cpb_w1  = (const float*)d_in[7];
  const float* cpb_b1  = (const float*)d_in[8];
  const float* cpb_w2  = (const float*)d_in[9];
  const float* cpb_b2  = (const float*)d_in[10];
  const float* es_ln1g = (const float*)d_in[11];
  const float* es_ln1b = (const float*)d_in[12];
  const float* es_wqkv = (const float*)d_in[13];
  const float* es_wo   = (const float*)d_in[14];
  const float* es_ln2g = (const float*)d_in[15];
  const float* es_ln2b = (const float*)d_in[16];
  const float* es_w1   = (const float*)d_in[17];
  const float* es_b1   = (const float*)d_in[18];
  const float* es_w2   = (const float*)d_in[19];
  const float* es_b2   = (const float*)d_in[20];
  const float* et_ln1g = (const float*)d_in[21];
  const float* et_ln1b = (const float*)d_in[22];
  const float* et_wqkv = (const float*)d_in[23];
  const float* et_wo   = (const float*)d_in[24];
  const float* et_ln2g = (const float*)d_in[25];
  const float* et_ln2b = (const float*)d_in[26];
  const float* et_w1   = (const float*)d_in[27];
  const float* et_b1   = (const float*)d_in[28];
  const float* et_w2   = (const float*)d_in[29];
  const float* et_b2   = (const float*)d_in[30];
  const float* ds_ln1g = (const float*)d_in[31];
  const float* ds_ln1b = (const float*)d_in[32];
  const float* ds_wqkv = (const float*)d_in[33];
  const float* ds_wo   = (const float*)d_in[34];
  // d_in[35..37] ds_clng/ds_clnb/ds_wq: mathematically dead (L=1 softmax == 1)
  const float* ds_wkv  = (const float*)d_in[38];
  const float* ds_cwo  = (const float*)d_in[39];
  const float* ds_ln2g = (const float*)d_in[40];
  const float* ds_ln2b = (const float*)d_in[41];
  const float* ds_w1   = (const float*)d_in[42];
  const float* ds_b1   = (const float*)d_in[43];
  const float* ds_w2   = (const float*)d_in[44];
  const float* ds_b2   = (const float*)d_in[45];
  const float* vq_inw  = (const float*)d_in[46];
  const float* vq_inb  = (const float*)d_in[47];
  const float* codebook= (const float*)d_in[48];
  const float* vq_outw = (const float*)d_in[49];
  const float* vq_outb = (const float*)d_in[50];
  const float* noise   = (const float*)d_in[51];
  const float* px_w    = (const float*)d_in[52];
  const float* px_b    = (const float*)d_in[53];
  float* out = (float*)d_out;

  // workspace layout (floats)
  float* ws = (float*)d_ws;
  float* xpe  = ws;                   // 4096*768  (also reused for pix)
  float* x    = xpe + 3145728;        // 4096*512
  float* lnb  = x + 2097152;          // 4096*512
  float* qkvb = lnb + 2097152;        // 4096*1536
  float* scr  = qkvb + 6291456;       // 8388608: scores OR ff1
  float* attn = scr + 8388608;        // 4096*512
  float* tmb  = attn + 2097152;       // 4096*512
  float* biasf= tmb + 2097152;        // 8*256*256
  float* table= biasf + 524288;       // 961*8
  float* feat = table + 7688;         // 8*512
  float* zbuf = feat + 4096;          // 8*256
  float* zqb  = zbuf + 2048;          // 8*256
  float* act  = zqb + 2048;           // 8*512
  float* vctx = act + 4096;           // 8*512
  float* ubuf = vctx + 4096;          // 8*512
  float* errb = ubuf + 4096;          // 8 (unused)
  // bf16 transposed weights (ushort), 16B-aligned tail
  u16* wbf    = (u16*)(errb + 8);
  u16* pe_wt  = wbf;                   // 512x768
  u16* qkv_wt = pe_wt + 393216;        // 6 x (1536x512)
  u16* wo_wt  = qkv_wt + 4718592;      // 6 x (512x512)
  u16* w1_wt  = wo_wt + 1572864;       // 6 x (2048x512)
  u16* w2_wt  = w1_wt + 6291456;       // 6 x (512x2048)
  u16* px_wt  = w2_wt + 6291456;       // 768x512

  const int M = 4096;

  // ---- weight cast+transpose (bf16, [N][K]) ----
  {
    TP6 pqkv = {es_wqkv, es_wqkv + 786432, et_wqkv, et_wqkv + 786432, ds_wqkv, ds_wqkv + 786432};
    wtrans_k<<<dim3(48, 16, 6), dim3(32, 8), 0, stream>>>(pqkv, qkv_wt, 512, 1536, 786432);
    TP6 pwo = {es_wo, es_wo + 262144, et_wo, et_wo + 262144, ds_wo, ds_wo + 262144};
    wtrans_k<<<dim3(16, 16, 6), dim3(32, 8), 0, stream>>>(pwo, wo_wt, 512, 512, 262144);
    TP6 pw1 = {es_w1, es_w1 + 1048576, et_w1, et_w1 + 1048576, ds_w1, ds_w1 + 1048576};
    wtrans_k<<<dim3(64, 16, 6), dim3(32, 8), 0, stream>>>(pw1, w1_wt, 512, 2048, 1048576);
    TP6 pw2 = {es_w2, es_w2 + 1048576, et_w2, et_w2 + 1048576, ds_w2, ds_w2 + 1048576};
    wtrans_k<<<dim3(16, 64, 6), dim3(32, 8), 0, stream>>>(pw2, w2_wt, 2048, 512, 1048576);
    TP6 ppe = {pe_w, pe_w, pe_w, pe_w, pe_w, pe_w};
    wtrans_k<<<dim3(16, 24, 1), dim3(32, 8), 0, stream>>>(ppe, pe_wt, 768, 512, 0);
    TP6 ppx = {px_w, px_w, px_w, px_w, px_w, px_w};
    wtrans_k<<<dim3(24, 16, 1), dim3(32, 8), 0, stream>>>(ppx, px_wt, 512, 768, 0);
  }

  // ---- patch embed ----
  pembed_k<<<4096, 256, 0, stream>>>(video, pe_ln1g, pe_ln1b, xpe);
  mgemm(stream, xpe, pe_wt, pe_b, nullptr, lnb, M, 512, 768, false);
  ln512_k<<<4096, 256, 0, stream>>>(lnb, pe_ln2g, pe_ln2b, x);

  // ---- CPB bias ----
  cpb_k<<<961, 64, 0, stream>>>(cpb_w1, cpb_b1, cpb_w2, cpb_b2, table);
  cpbexpand_k<<<256, 256, 0, stream>>>(table, biasf);

  // ---- encoder spatial (2 layers) ----
  for (int d = 0; d < 2; ++d) {
    const int li = 0 * 2 + d;
    ln512_k<<<4096, 256, 0, stream>>>(x, es_ln1g + d * 512, es_ln1b + d * 512, lnb);
    mgemm(stream, lnb, qkv_wt + (size_t)li * 786432, nullptr, nullptr, qkvb, M, 1536, 512, false);
    qk_k<<<dim3(4, 4, 128), 256, 0, stream>>>(qkvb, biasf, scr);
    softmax_k<<<8192, 256, 0, stream>>>(scr);
    pv_k<<<dim3(1, 4, 128), 256, 0, stream>>>(scr, qkvb, attn);
    mgemm(stream, attn, wo_wt + (size_t)li * 262144, nullptr, x, x, M, 512, 512, false);
    ln512_k<<<4096, 256, 0, stream>>>(x, es_ln2g + d * 512, es_ln2b + d * 512, lnb);
    mgemm(stream, lnb, w1_wt + (size_t)li * 1048576, es_b1 + d * 2048, nullptr, scr, M, 2048, 512, true);
    mgemm(stream, scr, w2_wt + (size_t)li * 1048576, es_b2 + d * 512, x, x, M, 512, 2048, false);
  }

  // ---- encoder temporal (2 layers) ----
  xpose_fwd_k<<<4096, 128, 0, stream>>>(x, tmb);
  for (int d = 0; d < 2; ++d) {
    const int li = 1 * 2 + d;
    ln512_k<<<4096, 256, 0, stream>>>(tmb, et_ln1g + d * 512, et_ln1b + d * 512, lnb);
    mgemm(stream, lnb, qkv_wt + (size_t)li * 786432, nullptr, nullptr, qkvb, M, 1536, 512, false);
    tattn_k<<<4096, 256, 0, stream>>>(qkvb, attn);
    mgemm(stream, attn, wo_wt + (size_t)li * 262144, nullptr, tmb, tmb, M, 512, 512, false);
    ln512_k<<<4096, 256, 0, stream>>>(tmb, et_ln2g + d * 512, et_ln2b + d * 512, lnb);
    mgemm(stream, lnb, w1_wt + (size_t)li * 1048576, et_b1 + d * 2048, nullptr, scr, M, 2048, 512, true);
    mgemm(stream, scr, w2_wt + (size_t)li * 1048576, et_b2 + d * 512, tmb, tmb, M, 512, 2048, false);
  }
  xpose_bwd_k<<<4096, 128, 0, stream>>>(tmb, x);

  // ---- NSVQ bottleneck ----
  featmean_k<<<dim3(8, 8), 256, 0, stream>>>(x, feat);
  vecmat8_k<512><<<4, 256, 0, stream>>>(feat, vq_inw, 256, 0, vq_inb, zbuf, 256);
  vq_k<<<8, 1024, 0, stream>>>(zbuf, codebook, noise, zqb);
  vecmat8_k<256><<<8, 256, 0, stream>>>(zqb, vq_outw, 512, 0, vq_outb, act, 512);

  // ---- decoder (2 layers) ----
  for (int d = 0; d < 2; ++d) {
    const int li = 2 * 2 + d;
    ln512_k<<<4096, 256, 0, stream>>>(x, ds_ln1g + d * 512, ds_ln1b + d * 512, lnb);
    mgemm(stream, lnb, qkv_wt + (size_t)li * 786432, nullptr, nullptr, qkvb, M, 1536, 512, false);
    qk_k<<<dim3(4, 4, 128), 256, 0, stream>>>(qkvb, biasf, scr);
    softmax_k<<<8192, 256, 0, stream>>>(scr);
    pv_k<<<dim3(1, 4, 128), 256, 0, stream>>>(scr, qkvb, attn);
    mgemm(stream, attn, wo_wt + (size_t)li * 262144, nullptr, x, x, M, 512, 512, false);
    // cross-attn: L=1 -> softmax==1 -> out = (ctx @ wkv_v) @ cwo, broadcast over sequence
    vecmat8_k<512><<<8, 256, 0, stream>>>(act, ds_wkv + (size_t)d * 512 * 1024, 1024, 512, nullptr, vctx, 512);
    vecmat8_k<512><<<8, 256, 0, stream>>>(vctx, ds_cwo + (size_t)d * 512 * 512, 512, 0, nullptr, ubuf, 512);
    bcastadd_k<<<4096, 128, 0, stream>>>(x, ubuf);
    ln512_k<<<4096, 256, 0, stream>>>(x, ds_ln2g + d * 512, ds_ln2b + d * 512, lnb);
    mgemm(stream, lnb, w1_wt + (size_t)li * 1048576, ds_b1 + d * 2048, nullptr, scr, M, 2048, 512, true);
    mgemm(stream, scr, w2_wt + (size_t)li * 1048576, ds_b2 + d * 512, x, x, M, 512, 2048, false);
  }

  // ---- pixel head + scatter ----
  mgemm(stream, x, px_wt, px_b, nullptr, xpe, M, 768, 512, false);
  scatter_k<<<4096, 256, 0, stream>>>(xpe, out);
}